// Round 11
// baseline (428.240 us; speedup 1.0000x reference)
//
#include <hip/hip_runtime.h>

// ---------- types ----------
typedef __attribute__((ext_vector_type(8))) _Float16 half8;
typedef __attribute__((ext_vector_type(4))) _Float16 half4v;
typedef __attribute__((ext_vector_type(2))) _Float16 half2v;
typedef __attribute__((ext_vector_type(4))) float float4v;

// MFMA wrappers. Host pass chokes on top-level __has_builtin dispatch,
// so guard with __HIP_DEVICE_COMPILE__.
__device__ __forceinline__ float4v mfma16x16x32_f16(half8 a, half8 b, float4v c) {
#if defined(__HIP_DEVICE_COMPILE__)
#if __has_builtin(__builtin_amdgcn_mfma_f32_16x16x32_f16)
  return __builtin_amdgcn_mfma_f32_16x16x32_f16(a, b, c, 0, 0, 0);
#elif __has_builtin(__builtin_amdgcn_mfma_f32_16x16x32f16)
  return __builtin_amdgcn_mfma_f32_16x16x32f16(a, b, c, 0, 0, 0);
#else
#error "no 16x16x32 f16 mfma"
#endif
#else
  (void)a; (void)b;
  return c;
#endif
}

__device__ __forceinline__ float4v mfma16x16x16_f16(half4v a, half4v b, float4v c) {
#if defined(__HIP_DEVICE_COMPILE__)
#if __has_builtin(__builtin_amdgcn_mfma_f32_16x16x16f16)
  return __builtin_amdgcn_mfma_f32_16x16x16f16(a, b, c, 0, 0, 0);
#elif __has_builtin(__builtin_amdgcn_mfma_f32_16x16x16_f16)
  return __builtin_amdgcn_mfma_f32_16x16x16_f16(a, b, c, 0, 0, 0);
#else
#error "no 16x16x16 f16 mfma"
#endif
#else
  (void)a; (void)b;
  return c;
#endif
}

// async global->LDS, 16B per lane. LDS dest must be wave-uniform base + lane*16.
__device__ __forceinline__ void gl_lds16(const unsigned short* g, unsigned short* l) {
#if defined(__HIP_DEVICE_COMPILE__)
#if __has_builtin(__builtin_amdgcn_global_load_lds)
  __builtin_amdgcn_global_load_lds(
      (const __attribute__((address_space(1))) unsigned int*)g,
      (__attribute__((address_space(3))) unsigned int*)l, 16, 0, 0);
#else
  *(uint4*)l = *(const uint4*)g;
#endif
#else
  (void)g; (void)l;
#endif
}

__device__ __forceinline__ float fexp2(float x) {
#if defined(__HIP_DEVICE_COMPILE__)
#if __has_builtin(__builtin_amdgcn_exp2f)
  return __builtin_amdgcn_exp2f(x);
#else
  return __expf(x * 0.6931471805599453f);
#endif
#else
  return x;
#endif
}

__device__ __forceinline__ float frcp(float x) {
#if defined(__HIP_DEVICE_COMPILE__)
#if __has_builtin(__builtin_amdgcn_rcpf)
  return __builtin_amdgcn_rcpf(x);
#else
  return 1.0f / x;
#endif
#else
  return 1.0f / x;
#endif
}

__device__ __forceinline__ half2v pk_f16(float a, float b) {
#if defined(__HIP_DEVICE_COMPILE__)
#if __has_builtin(__builtin_amdgcn_cvt_pkrtz)
  return __builtin_bit_cast(half2v, __builtin_amdgcn_cvt_pkrtz(a, b));
#else
  half2v r;
  r[0] = (_Float16)a;
  r[1] = (_Float16)b;
  return r;
#endif
#else
  half2v r;
  r[0] = (_Float16)a;
  r[1] = (_Float16)b;
  return r;
#endif
}

// s_setprio needs a CONSTANT integer argument (round-10 compile failure:
// a runtime int parameter is rejected before inlining). Template param makes
// it a constant expression at the builtin call site.
template <int P>
__device__ __forceinline__ void setprio() {
#if defined(__HIP_DEVICE_COMPILE__)
#if __has_builtin(__builtin_amdgcn_s_setprio)
  __builtin_amdgcn_s_setprio(P);
#endif
#endif
}

__device__ __forceinline__ unsigned short f2h(float f) {
  union { _Float16 h; unsigned short u; } v;
  v.h = (_Float16)f;
  return v.u;
}

// 16-lane (DPP row_ror) rotation-butterfly sum: every lane of each 16-group
// ends with the group total. 4 full-rate VALU adds, no LDS-pipe latency.
__device__ __forceinline__ float row_sum16(float x) {
#if defined(__HIP_DEVICE_COMPILE__)
#if __has_builtin(__builtin_amdgcn_update_dpp)
  int v;
  v = __builtin_bit_cast(int, x);
  x += __builtin_bit_cast(float, __builtin_amdgcn_update_dpp(0, v, 0x128, 0xF, 0xF, true));
  v = __builtin_bit_cast(int, x);
  x += __builtin_bit_cast(float, __builtin_amdgcn_update_dpp(0, v, 0x124, 0xF, 0xF, true));
  v = __builtin_bit_cast(int, x);
  x += __builtin_bit_cast(float, __builtin_amdgcn_update_dpp(0, v, 0x122, 0xF, 0xF, true));
  v = __builtin_bit_cast(int, x);
  x += __builtin_bit_cast(float, __builtin_amdgcn_update_dpp(0, v, 0x121, 0xF, 0xF, true));
  return x;
#else
  x += __shfl_xor(x, 1);
  x += __shfl_xor(x, 2);
  x += __shfl_xor(x, 4);
  x += __shfl_xor(x, 8);
  return x;
#endif
#else
  return x;
#endif
}

// ---------- merged fp32 -> fp16 converts (5 tensors, one dispatch) ----------
__global__ __launch_bounds__(256) void cvt_multi(
    const float* __restrict__ s0, unsigned short* __restrict__ d0, int n0,
    const float* __restrict__ s1, unsigned short* __restrict__ d1,
    const float* __restrict__ s2, unsigned short* __restrict__ d2,
    const float* __restrict__ s3, unsigned short* __restrict__ d3, int n13,
    const float* __restrict__ s4, unsigned short* __restrict__ d4, int n4c) {
  const int y = blockIdx.y;
  const float* s;
  unsigned short* d;
  int n;
  if (y == 0) { s = s0; d = d0; n = n0; }
  else if (y == 1) { s = s1; d = d1; n = n13; }
  else if (y == 2) { s = s2; d = d2; n = n13; }
  else if (y == 3) { s = s3; d = d3; n = n13; }
  else { s = s4; d = d4; n = n4c; }
  const int i = blockIdx.x * 256 + threadIdx.x;
  if (i >= n) return;
  float4 v = ((const float4*)s)[i];
  uint2 o;
  o.x = (unsigned)f2h(v.x) | ((unsigned)f2h(v.y) << 16);
  o.y = (unsigned)f2h(v.z) | ((unsigned)f2h(v.w) << 16);
  ((uint2*)d)[i] = o;
}

// ---------- shared GEMM core: 128x128 tile, K=512, 512 threads (8 waves 4x2) ----------
// 128x128 @ 32 KB LDS -> 4 blocks/CU. XOR chunk swizzle: LDS slot (row r,
// chunk sc) holds global chunk sc^(r&7); reader of chunk c uses c^(row&7);
// row&7 == col&7 since wm/wn/i*16 = 0 mod 8.
#define GEMM_CORE(WGPTR)                                                               \
  for (int k0 = 0; k0 < 512; k0 += 64) {                                               \
    _Pragma("unroll") for (int rnd = 0; rnd < 2; ++rnd) {                              \
      const int slot = rnd * 512 + tid;                                                \
      const int r = slot >> 3;                                                         \
      const int c = (slot & 7) ^ (r & 7);                                              \
      gl_lds16(Xbase + xrow0 + (size_t)r * 512 + (size_t)(k0 + c * 8), &Xs[slot * 8]); \
    }                                                                                  \
    _Pragma("unroll") for (int rnd = 0; rnd < 2; ++rnd) {                              \
      const int s2 = rnd * 512 + tid;                                                  \
      const int r = s2 >> 3;                                                           \
      const int c = (s2 & 7) ^ (r & 7);                                                \
      gl_lds16((WGPTR) + (size_t)r * 512 + k0 + c * 8, &Wt[s2 * 8]);                   \
    }                                                                                  \
    __syncthreads();                                                                   \
    _Pragma("unroll") for (int kk = 0; kk < 2; ++kk) {                                 \
      half8 af[2], bf[4];                                                              \
      const int ch = ((kk * 4 + grp) ^ (col & 7)) * 8;                                 \
      _Pragma("unroll") for (int i = 0; i < 2; ++i)                                    \
          af[i] = *(const half8*)&Xs[(wm + i * 16 + col) * 64 + ch];                   \
      _Pragma("unroll") for (int j = 0; j < 4; ++j)                                    \
          bf[j] = *(const half8*)&Wt[(wn + j * 16 + col) * 64 + ch];                   \
      _Pragma("unroll") for (int i = 0; i < 2; ++i)                                    \
          _Pragma("unroll") for (int j = 0; j < 4; ++j)                                \
              acc[i][j] = mfma16x16x32_f16(af[i], bf[j], acc[i][j]);                   \
    }                                                                                  \
    __syncthreads();                                                                   \
  }

// ---------- QKV projection GEMM, dual-output-set ----------
// z in [0,6): zz=z%3 picks {q,k,v}; mode=z/3 picks output set and weight mode.
// mt in [0,96): batch = mt/3, cpart = mt%3 -> 128-row tile = one batch's one
// chunk part (widx-uniform for the chunked weight dispatch).
__global__ __launch_bounds__(512) void gemm_qkv6(
    const unsigned short* __restrict__ X,
    const unsigned short* __restrict__ Wq, const unsigned short* __restrict__ Wk,
    const unsigned short* __restrict__ Wv,
    const float* __restrict__ bq, const float* __restrict__ bk, const float* __restrict__ bv,
    unsigned short* __restrict__ CqA, unsigned short* __restrict__ CkA,
    unsigned short* __restrict__ CvA, unsigned short* __restrict__ CqB,
    unsigned short* __restrict__ CkB, unsigned short* __restrict__ CvB,
    int widx_fixed) {
  const int nt = blockIdx.x, mt = blockIdx.y, z = blockIdx.z;
  const int zz = z % 3, mode = z / 3;
  const unsigned short* W = (zz == 0) ? Wq : ((zz == 1) ? Wk : Wv);
  const float* bias = (zz == 0) ? bq : ((zz == 1) ? bk : bv);
  unsigned short* C = mode ? ((zz == 0) ? CqB : ((zz == 1) ? CkB : CvB))
                           : ((zz == 0) ? CqA : ((zz == 1) ? CkA : CvA));
  const int cpart = mt % 3, batch = mt / 3;
  const int widx = mode ? (1 + cpart) : widx_fixed;
  W += (size_t)widx * 512 * 512;
  bias += widx * 512;

  const size_t grow0 = (size_t)batch * 384 + cpart * 128;
  const size_t xrow0 = grow0 * 512;
  const unsigned short* Xbase = X;

  __shared__ __align__(16) unsigned short Xs[1024 * 8];  // 128x64 f16 (16 KB)
  __shared__ __align__(16) unsigned short Wt[1024 * 8];  // 128x64 f16 (16 KB)
  const int tid = threadIdx.x, lane = tid & 63, w = tid >> 6;
  const int col = lane & 15, grp = lane >> 4;
  const int wm = (w >> 1) * 32, wn = (w & 1) * 64;

  const float4v zero4 = {0.f, 0.f, 0.f, 0.f};
  float4v acc[2][4];
#pragma unroll
  for (int i = 0; i < 2; ++i)
#pragma unroll
    for (int j = 0; j < 4; ++j) acc[i][j] = zero4;

  GEMM_CORE(W + (size_t)nt * 128 * 512)

#pragma unroll
  for (int j = 0; j < 4; ++j) {
    const int n = nt * 128 + wn + j * 16 + col;
    const float bj = bias[n];
#pragma unroll
    for (int i = 0; i < 2; ++i)
#pragma unroll
      for (int r = 0; r < 4; ++r) {
        const int m = wm + i * 16 + grp * 4 + r;
        C[(grow0 + m) * 512 + n] = f2h(acc[i][j][r] + bj);
      }
  }
}

// ---------- fusion GEMM: z = diff16 @ W^T ; out = tl2 + diff32*sigmoid(z) ----------
__global__ __launch_bounds__(512) void gemm_fusion(
    const unsigned short* __restrict__ X, const unsigned short* __restrict__ Wf,
    const float* __restrict__ dif, const float* __restrict__ tl2, float* __restrict__ outp) {
  const int nt = blockIdx.x, mt = blockIdx.y;
  const size_t grow0 = (size_t)mt * 128;
  const size_t xrow0 = grow0 * 512;
  const unsigned short* Xbase = X;

  __shared__ __align__(16) unsigned short Xs[1024 * 8];
  __shared__ __align__(16) unsigned short Wt[1024 * 8];
  const int tid = threadIdx.x, lane = tid & 63, w = tid >> 6;
  const int col = lane & 15, grp = lane >> 4;
  const int wm = (w >> 1) * 32, wn = (w & 1) * 64;

  const float4v zero4 = {0.f, 0.f, 0.f, 0.f};
  float4v acc[2][4];
#pragma unroll
  for (int i = 0; i < 2; ++i)
#pragma unroll
    for (int j = 0; j < 4; ++j) acc[i][j] = zero4;

  GEMM_CORE(Wf + (size_t)nt * 128 * 512)

#pragma unroll
  for (int j = 0; j < 4; ++j) {
    const int n = nt * 128 + wn + j * 16 + col;
#pragma unroll
    for (int i = 0; i < 2; ++i)
#pragma unroll
      for (int r = 0; r < 4; ++r) {
        const int m = wm + i * 16 + grp * 4 + r;
        const size_t off = (grow0 + m) * 512 + n;
        const float d = dif[off], t2 = tl2[off];
        const float sg = 1.0f / (1.0f + __expf(-acc[i][j][r]));
        outp[off] = t2 + d * sg;
      }
  }
}

// ---------- attention body, two-pass recompute, 512 threads ----------
// Round-6 champion structure: 2 barriers/block, f32 exp (f16 exp OVERFLOWS:
// |S|~40 -> e~1e15, round-4 failure), LDS-atomic Z, unroll 2.
// Round-11 micro-tuning: (a) V register loads issued BEFORE the K gather so
// their latency hides under the K staging sequence; (b) s_setprio(1) around
// the per-tile compute clusters — independent blocks per CU sit at different
// phases (mixed heavy/light, no cross-block sync), the measured-positive
// regime for setprio on attention.
template <int T>
__device__ __forceinline__ void attn_body(
    const unsigned short* __restrict__ Qb, const unsigned short* __restrict__ Kb,
    const unsigned short* __restrict__ Vb, const float* __restrict__ temp_base,
    const float* add_src,  // may alias diff32
    float* outp, int chunk_elems, int cb, int h, int b,
    const float* tl1_src,  // may alias outp (tail writes tl2 in place)
    unsigned short* diff16, float* diff32,
    unsigned short* KVt, float* Zs) {
  constexpr int NT = T / 16;
  constexpr int NSW = NT / 8;
  constexpr int SLAB = T * 32;
  const int base = b * (384 * 512) + cb * chunk_elems + h * SLAB;
  const float tl2e = temp_base[cb * 16 + h] * 1.4426950408889634f;

  const int tid = threadIdx.x, lane = tid & 63, w = tid >> 6;
  const int col = lane & 15, grp = lane >> 4;

  // zero the Z accumulators (covered by the staging barrier)
  if (tid < NT * 16) Zs[tid] = 0.f;

  // --- V fragments first: global -> registers; latency hides under K stage ---
  half8 vfr[NSW];
  {
    const unsigned short* Vg = Vb + base;
#pragma unroll
    for (int si = 0; si < NSW; ++si) {
      const int s = (w + si * 8) * 16 + col;
      union { unsigned short u[8]; half8 v; } t8;
#pragma unroll
      for (int i = 0; i < 8; ++i) t8.u[i] = Vg[(size_t)(grp * 8 + i) * T + s];
      vfr[si] = t8.v;
    }
  }
  // --- K -> LDS transposed [t][dd], row stride 40 shorts (80 B) ---
  {
    const unsigned short* src = Kb + base;
    constexpr int ITER = (T * 4) / 512;
#pragma unroll
    for (int p = 0; p < ITER; ++p) {
      const int f = p * 512 + tid;
      const int t = f >> 2, blk = (f & 3) * 8;
      unsigned short tmp[8];
#pragma unroll
      for (int i = 0; i < 8; ++i) tmp[i] = src[(size_t)(blk + i) * T + t];
      *(uint4*)&KVt[t * 40 + blk] = *(const uint4*)tmp;
    }
  }
  __syncthreads();

  const float4v zero4 = {0.f, 0.f, 0.f, 0.f};

  // --- pass 1: full Z via LDS atomics ---
#pragma unroll 2
  for (int tt = 0; tt < NT; ++tt) {
    half8 kf = *(const half8*)&KVt[(tt * 16 + col) * 40 + grp * 8];
    float z0 = 0.f, z1 = 0.f, z2 = 0.f, z3 = 0.f;
    setprio<1>();
#pragma unroll
    for (int si = 0; si < NSW; ++si) {
      float4v sv = mfma16x16x32_f16(kf, vfr[si], zero4);
      z0 += fexp2(sv[0] * tl2e);
      z1 += fexp2(sv[1] * tl2e);
      z2 += fexp2(sv[2] * tl2e);
      z3 += fexp2(sv[3] * tl2e);
    }
    setprio<0>();
    z0 = row_sum16(z0);
    z1 = row_sum16(z1);
    z2 = row_sum16(z2);
    z3 = row_sum16(z3);
    if (col == 0) {
      float* zp = &Zs[tt * 16 + grp * 4];
      atomicAdd(zp + 0, z0);
      atomicAdd(zp + 1, z1);
      atomicAdd(zp + 2, z2);
      atomicAdd(zp + 3, z3);
    }
  }
  __syncthreads();

  // --- pass 2: recompute S, normalize, PV ---
  const unsigned short* Qsl = Qb + base;
  float4v oacc[NSW][2];
#pragma unroll
  for (int si = 0; si < NSW; ++si) {
    oacc[si][0] = zero4;
    oacc[si][1] = zero4;
  }
#pragma unroll 2
  for (int tt = 0; tt < NT; ++tt) {
    const int toff = tt * 16 + grp * 4;
    half4v qa0 = *(const half4v*)(Qsl + col * T + toff);
    half4v qa1 = *(const half4v*)(Qsl + (16 + col) * T + toff);
    float4v zsv = *(const float4v*)&Zs[tt * 16 + grp * 4];
    const float zi0 = frcp(zsv[0]), zi1 = frcp(zsv[1]), zi2 = frcp(zsv[2]),
                zi3 = frcp(zsv[3]);
    half8 kf = *(const half8*)&KVt[(tt * 16 + col) * 40 + grp * 8];
    setprio<1>();
#pragma unroll
    for (int si = 0; si < NSW; ++si) {
      float4v sv = mfma16x16x32_f16(kf, vfr[si], zero4);
      half2v lo = pk_f16(fexp2(sv[0] * tl2e) * zi0, fexp2(sv[1] * tl2e) * zi1);
      half2v hi = pk_f16(fexp2(sv[2] * tl2e) * zi2, fexp2(sv[3] * tl2e) * zi3);
      half4v pb = __builtin_shufflevector(lo, hi, 0, 1, 2, 3);
      oacc[si][0] = mfma16x16x16_f16(qa0, pb, oacc[si][0]);
      oacc[si][1] = mfma16x16x16_f16(qa1, pb, oacc[si][1]);
    }
    setprio<0>();
  }

  // --- epilogue ---
#pragma unroll
  for (int si = 0; si < NSW; ++si) {
    const int s = (w + si * 8) * 16 + col;
#pragma unroll
    for (int m0 = 0; m0 < 2; ++m0) {
#pragma unroll
      for (int r = 0; r < 4; ++r) {
        const int dd = m0 * 16 + grp * 4 + r;
        const int off = base + dd * T + s;
        const float o = oacc[si][m0][r];
        float v = o;
        if (add_src) v += add_src[off];
        if (tl1_src) {
          // diff = tl1_final - tl2 = (concat + x_) - (out4 + x_) = concat - out4
          const float d = tl1_src[off] - o;
          diff16[off] = f2h(d);
          diff32[off] = d;  // in-place over add_src[off]: read above precedes
        }
        outp[off] = v;  // in-place over tl1_src[off]: read above precedes
      }
    }
  }
}

// Merged attention: block0 (T=384) + blocks1-3 chunks (T=128) in one dispatch.
// 2048 blocks, heavy/light interleaved (id&3). LDS ~32.3 KB;
// no occupancy pin (round-1's (512,8) pin forced spills).
__global__ __launch_bounds__(512) void attn_merged(
    const unsigned short* __restrict__ Q0, const unsigned short* __restrict__ K0,
    const unsigned short* __restrict__ V0, const unsigned short* __restrict__ Qc,
    const unsigned short* __restrict__ Kc, const unsigned short* __restrict__ Vc,
    const float* __restrict__ temp, float* xres, float* tl1) {
  __shared__ __align__(16) unsigned short Ks[384 * 40];
  __shared__ __align__(16) float Zs[24 * 16];
  const int id = blockIdx.x + 16 * (blockIdx.y + 32 * blockIdx.z);
  const int part = id & 3, rest = id >> 2;
  const int h = rest & 15, b = rest >> 4;
  if (part == 0)
    attn_body<384>(Q0, K0, V0, temp, nullptr, xres, 0, 0, h, b,
                   nullptr, nullptr, nullptr, Ks, Zs);
  else
    attn_body<128>(Qc, Kc, Vc, temp + 16, nullptr, tl1, 128 * 512, part - 1, h, b,
                   nullptr, nullptr, nullptr, Ks, Zs);
}

// Tail attention (block 4): tl2 = out4 + x_ written in place into tl1 buffer,
// diff (f32 and f16) written; diff32 lands in place over x_ (add_src).
__global__ __launch_bounds__(512) void attn_tail(
    const unsigned short* __restrict__ Q, const unsigned short* __restrict__ K,
    const unsigned short* __restrict__ V, const float* __restrict__ temp4,
    const float* add_src, float* tl12, unsigned short* __restrict__ diff16,
    float* diff32) {
  __shared__ __align__(16) unsigned short Ks[384 * 40];
  __shared__ __align__(16) float Zs[24 * 16];
  attn_body<384>(Q, K, V, temp4, add_src, tl12, 0, 0, blockIdx.x, blockIdx.y,
                 tl12, diff16, diff32, Ks, Zs);
}

// ---------- layernorm over rows of 512 of (a + c) -> fp16 ----------
__global__ __launch_bounds__(256) void ln_kernel(const float* __restrict__ a,
                                                 const float* __restrict__ c,
                                                 const float* __restrict__ g,
                                                 const float* __restrict__ bb,
                                                 unsigned short* __restrict__ y) {
  const int row = blockIdx.x * 4 + (threadIdx.x >> 6);
  const int lane = threadIdx.x & 63;
  const float* ar = a + (size_t)row * 512;
  const float* cr = c + (size_t)row * 512;
  float4 a0 = *(const float4*)&ar[lane * 8];
  float4 a1 = *(const float4*)&ar[lane * 8 + 4];
  float4 c0 = *(const float4*)&cr[lane * 8];
  float4 c1 = *(const float4*)&cr[lane * 8 + 4];
  float4 v0, v1;
  v0.x = a0.x + c0.x; v0.y = a0.y + c0.y; v0.z = a0.z + c0.z; v0.w = a0.w + c0.w;
  v1.x = a1.x + c1.x; v1.y = a1.y + c1.y; v1.z = a1.z + c1.z; v1.w = a1.w + c1.w;
  float s = v0.x + v0.y + v0.z + v0.w + v1.x + v1.y + v1.z + v1.w;
  float q = v0.x * v0.x + v0.y * v0.y + v0.z * v0.z + v0.w * v0.w +
            v1.x * v1.x + v1.y * v1.y + v1.z * v1.z + v1.w * v1.w;
#pragma unroll
  for (int m = 1; m < 64; m <<= 1) {
    s += __shfl_xor(s, m);
    q += __shfl_xor(q, m);
  }
  const float mean = s * (1.0f / 512.0f);
  const float var = q * (1.0f / 512.0f) - mean * mean;
  const float rs = rsqrtf(var + 1e-5f);
  float4 g0 = *(const float4*)&g[lane * 8];
  float4 g1 = *(const float4*)&g[lane * 8 + 4];
  float4 b0 = *(const float4*)&bb[lane * 8];
  float4 b1 = *(const float4*)&bb[lane * 8 + 4];
  uint4 o;
  o.x = (unsigned)f2h((v0.x - mean) * rs * g0.x + b0.x) |
        ((unsigned)f2h((v0.y - mean) * rs * g0.y + b0.y) << 16);
  o.y = (unsigned)f2h((v0.z - mean) * rs * g0.z + b0.z) |
        ((unsigned)f2h((v0.w - mean) * rs * g0.w + b0.w) << 16);
  o.z = (unsigned)f2h((v1.x - mean) * rs * g1.x + b1.x) |
        ((unsigned)f2h((v1.y - mean) * rs * g1.y + b1.y) << 16);
  o.w = (unsigned)f2h((v1.z - mean) * rs * g1.z + b1.z) |
        ((unsigned)f2h((v1.w - mean) * rs * g1.w + b1.w) << 16);
  *(uint4*)&y[(size_t)row * 512 + lane * 8] = o;
}

// ---------- launch ----------
extern "C" void kernel_launch(void* const* d_in, const int* in_sizes, int n_in,
                              void* d_out, int out_size, void* d_ws, size_t ws_size,
                              hipStream_t stream) {
  const float* x = (const float*)d_in[0];
  const float* qw = (const float*)d_in[1];
  const float* qb = (const float*)d_in[2];
  const float* kw = (const float*)d_in[3];
  const float* kb = (const float*)d_in[4];
  const float* vw = (const float*)d_in[5];
  const float* vb = (const float*)d_in[6];
  const float* temp = (const float*)d_in[7];
  const float* ln_g = (const float*)d_in[8];
  const float* ln_b = (const float*)d_in[9];
  const float* fus_w = (const float*)d_in[10];
  // fus_b (d_in[11]) cancels in the 2-way softmax; num_heads (d_in[12]) fixed at 16
  float* out = (float*)d_out;

  const size_t NE = (size_t)32 * 384 * 512;  // 6291456
  const size_t WE = (size_t)5 * 512 * 512;   // 1310720

  char* p = (char*)d_ws;
  auto alloc = [&](size_t bytes) {
    char* r = p;
    p += (bytes + 255) & ~(size_t)255;
    return r;
  };
  unsigned short* xb = (unsigned short*)alloc(NE * 2);
  unsigned short* wqb = (unsigned short*)alloc(WE * 2);
  unsigned short* wkb = (unsigned short*)alloc(WE * 2);
  unsigned short* wvb = (unsigned short*)alloc(WE * 2);
  unsigned short* fwb = (unsigned short*)alloc((size_t)512 * 512 * 2);
  unsigned short* Qb = (unsigned short*)alloc(NE * 2);
  unsigned short* Kb = (unsigned short*)alloc(NE * 2);
  unsigned short* Vb = (unsigned short*)alloc(NE * 2);
  float* xres = (float*)alloc(NE * 4);  // x_ , later diff32 (in place)
  float* tl1 = (float*)alloc(NE * 4);   // raw concat, later tl2 (in place)
  unsigned short* yb = (unsigned short*)alloc(NE * 2);  // Qc, LN out, later diff16

  // chunk QKV scratch: Qc shares yb; Kc/Vc live in d_out (exactly 2*NE*2 B),
  // overwritten by the final fusion GEMM.
  unsigned short* Qc = yb;
  unsigned short* Kc = (unsigned short*)out;
  unsigned short* Vc = Kc + NE;

  // all converts in one dispatch
  cvt_multi<<<dim3((int)(NE / 4 / 256), 5), 256, 0, stream>>>(
      x, xb, (int)(NE / 4), qw, wqb, kw, wkb, vw, wvb, (int)(WE / 4), fus_w, fwb,
      512 * 512 / 4);

  // projections for block 0 (-> set A) and blocks 1-3 (-> set B), one dispatch
  gemm_qkv6<<<dim3(4, 96, 6), 512, 0, stream>>>(xb, wqb, wkb, wvb, qb, kb, vb,
                                                Qb, Kb, Vb, Qc, Kc, Vc, 0);
  // attention block0 -> x_ (xres) and blocks1-3 -> raw concat (tl1), merged
  attn_merged<<<dim3(16, 32, 4), 512, 0, stream>>>(Qb, Kb, Vb, Qc, Kc, Vc, temp,
                                                   xres, tl1);
  // layernorm(tl1raw + x_) -> yb (fp16)
  ln_kernel<<<12288 / 4, 256, 0, stream>>>(tl1, xres, ln_g, ln_b, yb);
  // block 4 projections (set A reused)
  gemm_qkv6<<<dim3(4, 96, 3), 512, 0, stream>>>(yb, wqb, wkb, wvb, qb, kb, vb,
                                                Qb, Kb, Vb, Qb, Kb, Vb, 4);
  // block 4 attention: tl2 -> tl1 (in place), diff16 -> yb, diff32 -> xres
  attn_tail<<<dim3(16, 32, 1), 512, 0, stream>>>(Qb, Kb, Vb, temp + 64, xres, tl1,
                                                 yb, xres);
  // fusion: out = tl2 + diff32 * sigmoid(diff16 @ fus_w^T)
  gemm_fusion<<<dim3(4, 96), 512, 0, stream>>>(yb, fwb, xres, tl1, out);

  (void)in_sizes; (void)n_in; (void)out_size; (void)ws_size;
}

// Round 12
// 411.099 us; speedup vs baseline: 1.0417x; 1.0417x over previous
//
#include <hip/hip_runtime.h>

// ---------- types ----------
typedef __attribute__((ext_vector_type(8))) _Float16 half8;
typedef __attribute__((ext_vector_type(4))) _Float16 half4v;
typedef __attribute__((ext_vector_type(2))) _Float16 half2v;
typedef __attribute__((ext_vector_type(4))) float float4v;

// MFMA wrappers. Host pass chokes on top-level __has_builtin dispatch,
// so guard with __HIP_DEVICE_COMPILE__.
__device__ __forceinline__ float4v mfma16x16x32_f16(half8 a, half8 b, float4v c) {
#if defined(__HIP_DEVICE_COMPILE__)
#if __has_builtin(__builtin_amdgcn_mfma_f32_16x16x32_f16)
  return __builtin_amdgcn_mfma_f32_16x16x32_f16(a, b, c, 0, 0, 0);
#elif __has_builtin(__builtin_amdgcn_mfma_f32_16x16x32f16)
  return __builtin_amdgcn_mfma_f32_16x16x32f16(a, b, c, 0, 0, 0);
#else
#error "no 16x16x32 f16 mfma"
#endif
#else
  (void)a; (void)b;
  return c;
#endif
}

__device__ __forceinline__ float4v mfma16x16x16_f16(half4v a, half4v b, float4v c) {
#if defined(__HIP_DEVICE_COMPILE__)
#if __has_builtin(__builtin_amdgcn_mfma_f32_16x16x16f16)
  return __builtin_amdgcn_mfma_f32_16x16x16f16(a, b, c, 0, 0, 0);
#elif __has_builtin(__builtin_amdgcn_mfma_f32_16x16x16_f16)
  return __builtin_amdgcn_mfma_f32_16x16x16_f16(a, b, c, 0, 0, 0);
#else
#error "no 16x16x16 f16 mfma"
#endif
#else
  (void)a; (void)b;
  return c;
#endif
}

// async global->LDS, 16B per lane. LDS dest must be wave-uniform base + lane*16.
__device__ __forceinline__ void gl_lds16(const unsigned short* g, unsigned short* l) {
#if defined(__HIP_DEVICE_COMPILE__)
#if __has_builtin(__builtin_amdgcn_global_load_lds)
  __builtin_amdgcn_global_load_lds(
      (const __attribute__((address_space(1))) unsigned int*)g,
      (__attribute__((address_space(3))) unsigned int*)l, 16, 0, 0);
#else
  *(uint4*)l = *(const uint4*)g;
#endif
#else
  (void)g; (void)l;
#endif
}

__device__ __forceinline__ float fexp2(float x) {
#if defined(__HIP_DEVICE_COMPILE__)
#if __has_builtin(__builtin_amdgcn_exp2f)
  return __builtin_amdgcn_exp2f(x);
#else
  return __expf(x * 0.6931471805599453f);
#endif
#else
  return x;
#endif
}

__device__ __forceinline__ float frcp(float x) {
#if defined(__HIP_DEVICE_COMPILE__)
#if __has_builtin(__builtin_amdgcn_rcpf)
  return __builtin_amdgcn_rcpf(x);
#else
  return 1.0f / x;
#endif
#else
  return 1.0f / x;
#endif
}

__device__ __forceinline__ half2v pk_f16(float a, float b) {
#if defined(__HIP_DEVICE_COMPILE__)
#if __has_builtin(__builtin_amdgcn_cvt_pkrtz)
  return __builtin_bit_cast(half2v, __builtin_amdgcn_cvt_pkrtz(a, b));
#else
  half2v r;
  r[0] = (_Float16)a;
  r[1] = (_Float16)b;
  return r;
#endif
#else
  half2v r;
  r[0] = (_Float16)a;
  r[1] = (_Float16)b;
  return r;
#endif
}

// s_setprio needs a CONSTANT integer argument (round-10 compile failure:
// a runtime int parameter is rejected before inlining). Template param makes
// it a constant expression at the builtin call site.
template <int P>
__device__ __forceinline__ void setprio() {
#if defined(__HIP_DEVICE_COMPILE__)
#if __has_builtin(__builtin_amdgcn_s_setprio)
  __builtin_amdgcn_s_setprio(P);
#endif
#endif
}

__device__ __forceinline__ unsigned short f2h(float f) {
  union { _Float16 h; unsigned short u; } v;
  v.h = (_Float16)f;
  return v.u;
}

// 16-lane (DPP row_ror) rotation-butterfly sum: every lane of each 16-group
// ends with the group total. 4 full-rate VALU adds, no LDS-pipe latency.
__device__ __forceinline__ float row_sum16(float x) {
#if defined(__HIP_DEVICE_COMPILE__)
#if __has_builtin(__builtin_amdgcn_update_dpp)
  int v;
  v = __builtin_bit_cast(int, x);
  x += __builtin_bit_cast(float, __builtin_amdgcn_update_dpp(0, v, 0x128, 0xF, 0xF, true));
  v = __builtin_bit_cast(int, x);
  x += __builtin_bit_cast(float, __builtin_amdgcn_update_dpp(0, v, 0x124, 0xF, 0xF, true));
  v = __builtin_bit_cast(int, x);
  x += __builtin_bit_cast(float, __builtin_amdgcn_update_dpp(0, v, 0x122, 0xF, 0xF, true));
  v = __builtin_bit_cast(int, x);
  x += __builtin_bit_cast(float, __builtin_amdgcn_update_dpp(0, v, 0x121, 0xF, 0xF, true));
  return x;
#else
  x += __shfl_xor(x, 1);
  x += __shfl_xor(x, 2);
  x += __shfl_xor(x, 4);
  x += __shfl_xor(x, 8);
  return x;
#endif
#else
  return x;
#endif
}

// ---------- merged fp32 -> fp16 converts (5 tensors, one dispatch) ----------
__global__ __launch_bounds__(256) void cvt_multi(
    const float* __restrict__ s0, unsigned short* __restrict__ d0, int n0,
    const float* __restrict__ s1, unsigned short* __restrict__ d1,
    const float* __restrict__ s2, unsigned short* __restrict__ d2,
    const float* __restrict__ s3, unsigned short* __restrict__ d3, int n13,
    const float* __restrict__ s4, unsigned short* __restrict__ d4, int n4c) {
  const int y = blockIdx.y;
  const float* s;
  unsigned short* d;
  int n;
  if (y == 0) { s = s0; d = d0; n = n0; }
  else if (y == 1) { s = s1; d = d1; n = n13; }
  else if (y == 2) { s = s2; d = d2; n = n13; }
  else if (y == 3) { s = s3; d = d3; n = n13; }
  else { s = s4; d = d4; n = n4c; }
  const int i = blockIdx.x * 256 + threadIdx.x;
  if (i >= n) return;
  float4 v = ((const float4*)s)[i];
  uint2 o;
  o.x = (unsigned)f2h(v.x) | ((unsigned)f2h(v.y) << 16);
  o.y = (unsigned)f2h(v.z) | ((unsigned)f2h(v.w) << 16);
  ((uint2*)d)[i] = o;
}

// ---------- shared GEMM core: 128x128 tile, K=512, 512 threads (8 waves 4x2) ----------
// 128x128 @ 32 KB LDS -> 4 blocks/CU. XOR chunk swizzle: LDS slot (row r,
// chunk sc) holds global chunk sc^(r&7); reader of chunk c uses c^(row&7);
// row&7 == col&7 since wm/wn/i*16 = 0 mod 8.
#define GEMM_CORE(WGPTR)                                                               \
  for (int k0 = 0; k0 < 512; k0 += 64) {                                               \
    _Pragma("unroll") for (int rnd = 0; rnd < 2; ++rnd) {                              \
      const int slot = rnd * 512 + tid;                                                \
      const int r = slot >> 3;                                                         \
      const int c = (slot & 7) ^ (r & 7);                                              \
      gl_lds16(Xbase + xrow0 + (size_t)r * 512 + (size_t)(k0 + c * 8), &Xs[slot * 8]); \
    }                                                                                  \
    _Pragma("unroll") for (int rnd = 0; rnd < 2; ++rnd) {                              \
      const int s2 = rnd * 512 + tid;                                                  \
      const int r = s2 >> 3;                                                           \
      const int c = (s2 & 7) ^ (r & 7);                                                \
      gl_lds16((WGPTR) + (size_t)r * 512 + k0 + c * 8, &Wt[s2 * 8]);                   \
    }                                                                                  \
    __syncthreads();                                                                   \
    _Pragma("unroll") for (int kk = 0; kk < 2; ++kk) {                                 \
      half8 af[2], bf[4];                                                              \
      const int ch = ((kk * 4 + grp) ^ (col & 7)) * 8;                                 \
      _Pragma("unroll") for (int i = 0; i < 2; ++i)                                    \
          af[i] = *(const half8*)&Xs[(wm + i * 16 + col) * 64 + ch];                   \
      _Pragma("unroll") for (int j = 0; j < 4; ++j)                                    \
          bf[j] = *(const half8*)&Wt[(wn + j * 16 + col) * 64 + ch];                   \
      _Pragma("unroll") for (int i = 0; i < 2; ++i)                                    \
          _Pragma("unroll") for (int j = 0; j < 4; ++j)                                \
              acc[i][j] = mfma16x16x32_f16(af[i], bf[j], acc[i][j]);                   \
    }                                                                                  \
    __syncthreads();                                                                   \
  }

// ---------- QKV projection GEMM, dual-output-set ----------
// z in [0,6): zz=z%3 picks {q,k,v}; mode=z/3 picks output set and weight mode.
// mt in [0,96): batch = mt/3, cpart = mt%3 -> 128-row tile = one batch's one
// chunk part (widx-uniform for the chunked weight dispatch).
__global__ __launch_bounds__(512) void gemm_qkv6(
    const unsigned short* __restrict__ X,
    const unsigned short* __restrict__ Wq, const unsigned short* __restrict__ Wk,
    const unsigned short* __restrict__ Wv,
    const float* __restrict__ bq, const float* __restrict__ bk, const float* __restrict__ bv,
    unsigned short* __restrict__ CqA, unsigned short* __restrict__ CkA,
    unsigned short* __restrict__ CvA, unsigned short* __restrict__ CqB,
    unsigned short* __restrict__ CkB, unsigned short* __restrict__ CvB,
    int widx_fixed) {
  const int nt = blockIdx.x, mt = blockIdx.y, z = blockIdx.z;
  const int zz = z % 3, mode = z / 3;
  const unsigned short* W = (zz == 0) ? Wq : ((zz == 1) ? Wk : Wv);
  const float* bias = (zz == 0) ? bq : ((zz == 1) ? bk : bv);
  unsigned short* C = mode ? ((zz == 0) ? CqB : ((zz == 1) ? CkB : CvB))
                           : ((zz == 0) ? CqA : ((zz == 1) ? CkA : CvA));
  const int cpart = mt % 3, batch = mt / 3;
  const int widx = mode ? (1 + cpart) : widx_fixed;
  W += (size_t)widx * 512 * 512;
  bias += widx * 512;

  const size_t grow0 = (size_t)batch * 384 + cpart * 128;
  const size_t xrow0 = grow0 * 512;
  const unsigned short* Xbase = X;

  __shared__ __align__(16) unsigned short Xs[1024 * 8];  // 128x64 f16 (16 KB)
  __shared__ __align__(16) unsigned short Wt[1024 * 8];  // 128x64 f16 (16 KB)
  const int tid = threadIdx.x, lane = tid & 63, w = tid >> 6;
  const int col = lane & 15, grp = lane >> 4;
  const int wm = (w >> 1) * 32, wn = (w & 1) * 64;

  const float4v zero4 = {0.f, 0.f, 0.f, 0.f};
  float4v acc[2][4];
#pragma unroll
  for (int i = 0; i < 2; ++i)
#pragma unroll
    for (int j = 0; j < 4; ++j) acc[i][j] = zero4;

  GEMM_CORE(W + (size_t)nt * 128 * 512)

#pragma unroll
  for (int j = 0; j < 4; ++j) {
    const int n = nt * 128 + wn + j * 16 + col;
    const float bj = bias[n];
#pragma unroll
    for (int i = 0; i < 2; ++i)
#pragma unroll
      for (int r = 0; r < 4; ++r) {
        const int m = wm + i * 16 + grp * 4 + r;
        C[(grow0 + m) * 512 + n] = f2h(acc[i][j][r] + bj);
      }
  }
}

// ---------- fusion GEMM: z = diff16 @ W^T ; out = tl2 + diff32*sigmoid(z) ----------
__global__ __launch_bounds__(512) void gemm_fusion(
    const unsigned short* __restrict__ X, const unsigned short* __restrict__ Wf,
    const float* __restrict__ dif, const float* __restrict__ tl2, float* __restrict__ outp) {
  const int nt = blockIdx.x, mt = blockIdx.y;
  const size_t grow0 = (size_t)mt * 128;
  const size_t xrow0 = grow0 * 512;
  const unsigned short* Xbase = X;

  __shared__ __align__(16) unsigned short Xs[1024 * 8];
  __shared__ __align__(16) unsigned short Wt[1024 * 8];
  const int tid = threadIdx.x, lane = tid & 63, w = tid >> 6;
  const int col = lane & 15, grp = lane >> 4;
  const int wm = (w >> 1) * 32, wn = (w & 1) * 64;

  const float4v zero4 = {0.f, 0.f, 0.f, 0.f};
  float4v acc[2][4];
#pragma unroll
  for (int i = 0; i < 2; ++i)
#pragma unroll
    for (int j = 0; j < 4; ++j) acc[i][j] = zero4;

  GEMM_CORE(Wf + (size_t)nt * 128 * 512)

#pragma unroll
  for (int j = 0; j < 4; ++j) {
    const int n = nt * 128 + wn + j * 16 + col;
#pragma unroll
    for (int i = 0; i < 2; ++i)
#pragma unroll
      for (int r = 0; r < 4; ++r) {
        const int m = wm + i * 16 + grp * 4 + r;
        const size_t off = (grow0 + m) * 512 + n;
        const float d = dif[off], t2 = tl2[off];
        const float sg = 1.0f / (1.0f + __expf(-acc[i][j][r]));
        outp[off] = t2 + d * sg;
      }
  }
}

// ---------- attention body, two-pass recompute, 512 threads ----------
// Round-6 champion structure: 2 barriers/block, f32 exp (f16 exp OVERFLOWS:
// |S|~40 -> e~1e15, round-4 failure), LDS-atomic Z, unroll 2.
// V register loads issued BEFORE the K gather (latency hides under staging).
// PRIO: s_setprio(1) around per-tile compute — POSITIVE in attn_merged
// (mixed heavy/light blocks at different phases; r11: 138->130 us, occ
// 20.5->27.9%) but the r11 total regression localized to attn_tail (all
// blocks lockstep, the setprio-negative regime per m190) -> tail gets
// PRIO=false via if constexpr.
template <int T, bool PRIO>
__device__ __forceinline__ void attn_body(
    const unsigned short* __restrict__ Qb, const unsigned short* __restrict__ Kb,
    const unsigned short* __restrict__ Vb, const float* __restrict__ temp_base,
    const float* add_src,  // may alias diff32
    float* outp, int chunk_elems, int cb, int h, int b,
    const float* tl1_src,  // may alias outp (tail writes tl2 in place)
    unsigned short* diff16, float* diff32,
    unsigned short* KVt, float* Zs) {
  constexpr int NT = T / 16;
  constexpr int NSW = NT / 8;
  constexpr int SLAB = T * 32;
  const int base = b * (384 * 512) + cb * chunk_elems + h * SLAB;
  const float tl2e = temp_base[cb * 16 + h] * 1.4426950408889634f;

  const int tid = threadIdx.x, lane = tid & 63, w = tid >> 6;
  const int col = lane & 15, grp = lane >> 4;

  // zero the Z accumulators (covered by the staging barrier)
  if (tid < NT * 16) Zs[tid] = 0.f;

  // --- V fragments first: global -> registers; latency hides under K stage ---
  half8 vfr[NSW];
  {
    const unsigned short* Vg = Vb + base;
#pragma unroll
    for (int si = 0; si < NSW; ++si) {
      const int s = (w + si * 8) * 16 + col;
      union { unsigned short u[8]; half8 v; } t8;
#pragma unroll
      for (int i = 0; i < 8; ++i) t8.u[i] = Vg[(size_t)(grp * 8 + i) * T + s];
      vfr[si] = t8.v;
    }
  }
  // --- K -> LDS transposed [t][dd], row stride 40 shorts (80 B) ---
  {
    const unsigned short* src = Kb + base;
    constexpr int ITER = (T * 4) / 512;
#pragma unroll
    for (int p = 0; p < ITER; ++p) {
      const int f = p * 512 + tid;
      const int t = f >> 2, blk = (f & 3) * 8;
      unsigned short tmp[8];
#pragma unroll
      for (int i = 0; i < 8; ++i) tmp[i] = src[(size_t)(blk + i) * T + t];
      *(uint4*)&KVt[t * 40 + blk] = *(const uint4*)tmp;
    }
  }
  __syncthreads();

  const float4v zero4 = {0.f, 0.f, 0.f, 0.f};

  // --- pass 1: full Z via LDS atomics ---
#pragma unroll 2
  for (int tt = 0; tt < NT; ++tt) {
    half8 kf = *(const half8*)&KVt[(tt * 16 + col) * 40 + grp * 8];
    float z0 = 0.f, z1 = 0.f, z2 = 0.f, z3 = 0.f;
    if constexpr (PRIO) setprio<1>();
#pragma unroll
    for (int si = 0; si < NSW; ++si) {
      float4v sv = mfma16x16x32_f16(kf, vfr[si], zero4);
      z0 += fexp2(sv[0] * tl2e);
      z1 += fexp2(sv[1] * tl2e);
      z2 += fexp2(sv[2] * tl2e);
      z3 += fexp2(sv[3] * tl2e);
    }
    if constexpr (PRIO) setprio<0>();
    z0 = row_sum16(z0);
    z1 = row_sum16(z1);
    z2 = row_sum16(z2);
    z3 = row_sum16(z3);
    if (col == 0) {
      float* zp = &Zs[tt * 16 + grp * 4];
      atomicAdd(zp + 0, z0);
      atomicAdd(zp + 1, z1);
      atomicAdd(zp + 2, z2);
      atomicAdd(zp + 3, z3);
    }
  }
  __syncthreads();

  // --- pass 2: recompute S, normalize, PV ---
  const unsigned short* Qsl = Qb + base;
  float4v oacc[NSW][2];
#pragma unroll
  for (int si = 0; si < NSW; ++si) {
    oacc[si][0] = zero4;
    oacc[si][1] = zero4;
  }
#pragma unroll 2
  for (int tt = 0; tt < NT; ++tt) {
    const int toff = tt * 16 + grp * 4;
    half4v qa0 = *(const half4v*)(Qsl + col * T + toff);
    half4v qa1 = *(const half4v*)(Qsl + (16 + col) * T + toff);
    float4v zsv = *(const float4v*)&Zs[tt * 16 + grp * 4];
    const float zi0 = frcp(zsv[0]), zi1 = frcp(zsv[1]), zi2 = frcp(zsv[2]),
                zi3 = frcp(zsv[3]);
    half8 kf = *(const half8*)&KVt[(tt * 16 + col) * 40 + grp * 8];
    if constexpr (PRIO) setprio<1>();
#pragma unroll
    for (int si = 0; si < NSW; ++si) {
      float4v sv = mfma16x16x32_f16(kf, vfr[si], zero4);
      half2v lo = pk_f16(fexp2(sv[0] * tl2e) * zi0, fexp2(sv[1] * tl2e) * zi1);
      half2v hi = pk_f16(fexp2(sv[2] * tl2e) * zi2, fexp2(sv[3] * tl2e) * zi3);
      half4v pb = __builtin_shufflevector(lo, hi, 0, 1, 2, 3);
      oacc[si][0] = mfma16x16x16_f16(qa0, pb, oacc[si][0]);
      oacc[si][1] = mfma16x16x16_f16(qa1, pb, oacc[si][1]);
    }
    if constexpr (PRIO) setprio<0>();
  }

  // --- epilogue ---
#pragma unroll
  for (int si = 0; si < NSW; ++si) {
    const int s = (w + si * 8) * 16 + col;
#pragma unroll
    for (int m0 = 0; m0 < 2; ++m0) {
#pragma unroll
      for (int r = 0; r < 4; ++r) {
        const int dd = m0 * 16 + grp * 4 + r;
        const int off = base + dd * T + s;
        const float o = oacc[si][m0][r];
        float v = o;
        if (add_src) v += add_src[off];
        if (tl1_src) {
          // diff = tl1_final - tl2 = (concat + x_) - (out4 + x_) = concat - out4
          const float d = tl1_src[off] - o;
          diff16[off] = f2h(d);
          diff32[off] = d;  // in-place over add_src[off]: read above precedes
        }
        outp[off] = v;  // in-place over tl1_src[off]: read above precedes
      }
    }
  }
}

// Merged attention: block0 (T=384) + blocks1-3 chunks (T=128) in one dispatch.
// 2048 blocks, heavy/light interleaved (id&3). LDS ~32.3 KB;
// no occupancy pin (round-1's (512,8) pin forced spills). PRIO=true.
__global__ __launch_bounds__(512) void attn_merged(
    const unsigned short* __restrict__ Q0, const unsigned short* __restrict__ K0,
    const unsigned short* __restrict__ V0, const unsigned short* __restrict__ Qc,
    const unsigned short* __restrict__ Kc, const unsigned short* __restrict__ Vc,
    const float* __restrict__ temp, float* xres, float* tl1) {
  __shared__ __align__(16) unsigned short Ks[384 * 40];
  __shared__ __align__(16) float Zs[24 * 16];
  const int id = blockIdx.x + 16 * (blockIdx.y + 32 * blockIdx.z);
  const int part = id & 3, rest = id >> 2;
  const int h = rest & 15, b = rest >> 4;
  if (part == 0)
    attn_body<384, true>(Q0, K0, V0, temp, nullptr, xres, 0, 0, h, b,
                         nullptr, nullptr, nullptr, Ks, Zs);
  else
    attn_body<128, true>(Qc, Kc, Vc, temp + 16, nullptr, tl1, 128 * 512, part - 1, h, b,
                         nullptr, nullptr, nullptr, Ks, Zs);
}

// Tail attention (block 4): tl2 = out4 + x_ written in place into tl1 buffer,
// diff (f32 and f16) written; diff32 lands in place over x_ (add_src).
// PRIO=false: 512 co-resident lockstep blocks are the setprio-NEGATIVE regime
// (r11 total regression localized here, +32 us).
__global__ __launch_bounds__(512) void attn_tail(
    const unsigned short* __restrict__ Q, const unsigned short* __restrict__ K,
    const unsigned short* __restrict__ V, const float* __restrict__ temp4,
    const float* add_src, float* tl12, unsigned short* __restrict__ diff16,
    float* diff32) {
  __shared__ __align__(16) unsigned short Ks[384 * 40];
  __shared__ __align__(16) float Zs[24 * 16];
  attn_body<384, false>(Q, K, V, temp4, add_src, tl12, 0, 0, blockIdx.x, blockIdx.y,
                        tl12, diff16, diff32, Ks, Zs);
}

// ---------- layernorm over rows of 512 of (a + c) -> fp16 ----------
__global__ __launch_bounds__(256) void ln_kernel(const float* __restrict__ a,
                                                 const float* __restrict__ c,
                                                 const float* __restrict__ g,
                                                 const float* __restrict__ bb,
                                                 unsigned short* __restrict__ y) {
  const int row = blockIdx.x * 4 + (threadIdx.x >> 6);
  const int lane = threadIdx.x & 63;
  const float* ar = a + (size_t)row * 512;
  const float* cr = c + (size_t)row * 512;
  float4 a0 = *(const float4*)&ar[lane * 8];
  float4 a1 = *(const float4*)&ar[lane * 8 + 4];
  float4 c0 = *(const float4*)&cr[lane * 8];
  float4 c1 = *(const float4*)&cr[lane * 8 + 4];
  float4 v0, v1;
  v0.x = a0.x + c0.x; v0.y = a0.y + c0.y; v0.z = a0.z + c0.z; v0.w = a0.w + c0.w;
  v1.x = a1.x + c1.x; v1.y = a1.y + c1.y; v1.z = a1.z + c1.z; v1.w = a1.w + c1.w;
  float s = v0.x + v0.y + v0.z + v0.w + v1.x + v1.y + v1.z + v1.w;
  float q = v0.x * v0.x + v0.y * v0.y + v0.z * v0.z + v0.w * v0.w +
            v1.x * v1.x + v1.y * v1.y + v1.z * v1.z + v1.w * v1.w;
#pragma unroll
  for (int m = 1; m < 64; m <<= 1) {
    s += __shfl_xor(s, m);
    q += __shfl_xor(q, m);
  }
  const float mean = s * (1.0f / 512.0f);
  const float var = q * (1.0f / 512.0f) - mean * mean;
  const float rs = rsqrtf(var + 1e-5f);
  float4 g0 = *(const float4*)&g[lane * 8];
  float4 g1 = *(const float4*)&g[lane * 8 + 4];
  float4 b0 = *(const float4*)&bb[lane * 8];
  float4 b1 = *(const float4*)&bb[lane * 8 + 4];
  uint4 o;
  o.x = (unsigned)f2h((v0.x - mean) * rs * g0.x + b0.x) |
        ((unsigned)f2h((v0.y - mean) * rs * g0.y + b0.y) << 16);
  o.y = (unsigned)f2h((v0.z - mean) * rs * g0.z + b0.z) |
        ((unsigned)f2h((v0.w - mean) * rs * g0.w + b0.w) << 16);
  o.z = (unsigned)f2h((v1.x - mean) * rs * g1.x + b1.x) |
        ((unsigned)f2h((v1.y - mean) * rs * g1.y + b1.y) << 16);
  o.w = (unsigned)f2h((v1.z - mean) * rs * g1.z + b1.z) |
        ((unsigned)f2h((v1.w - mean) * rs * g1.w + b1.w) << 16);
  *(uint4*)&y[(size_t)row * 512 + lane * 8] = o;
}

// ---------- launch ----------
extern "C" void kernel_launch(void* const* d_in, const int* in_sizes, int n_in,
                              void* d_out, int out_size, void* d_ws, size_t ws_size,
                              hipStream_t stream) {
  const float* x = (const float*)d_in[0];
  const float* qw = (const float*)d_in[1];
  const float* qb = (const float*)d_in[2];
  const float* kw = (const float*)d_in[3];
  const float* kb = (const float*)d_in[4];
  const float* vw = (const float*)d_in[5];
  const float* vb = (const float*)d_in[6];
  const float* temp = (const float*)d_in[7];
  const float* ln_g = (const float*)d_in[8];
  const float* ln_b = (const float*)d_in[9];
  const float* fus_w = (const float*)d_in[10];
  // fus_b (d_in[11]) cancels in the 2-way softmax; num_heads (d_in[12]) fixed at 16
  float* out = (float*)d_out;

  const size_t NE = (size_t)32 * 384 * 512;  // 6291456
  const size_t WE = (size_t)5 * 512 * 512;   // 1310720

  char* p = (char*)d_ws;
  auto alloc = [&](size_t bytes) {
    char* r = p;
    p += (bytes + 255) & ~(size_t)255;
    return r;
  };
  unsigned short* xb = (unsigned short*)alloc(NE * 2);
  unsigned short* wqb = (unsigned short*)alloc(WE * 2);
  unsigned short* wkb = (unsigned short*)alloc(WE * 2);
  unsigned short* wvb = (unsigned short*)alloc(WE * 2);
  unsigned short* fwb = (unsigned short*)alloc((size_t)512 * 512 * 2);
  unsigned short* Qb = (unsigned short*)alloc(NE * 2);
  unsigned short* Kb = (unsigned short*)alloc(NE * 2);
  unsigned short* Vb = (unsigned short*)alloc(NE * 2);
  float* xres = (float*)alloc(NE * 4);  // x_ , later diff32 (in place)
  float* tl1 = (float*)alloc(NE * 4);   // raw concat, later tl2 (in place)
  unsigned short* yb = (unsigned short*)alloc(NE * 2);  // Qc, LN out, later diff16

  // chunk QKV scratch: Qc shares yb; Kc/Vc live in d_out (exactly 2*NE*2 B),
  // overwritten by the final fusion GEMM.
  unsigned short* Qc = yb;
  unsigned short* Kc = (unsigned short*)out;
  unsigned short* Vc = Kc + NE;

  // all converts in one dispatch
  cvt_multi<<<dim3((int)(NE / 4 / 256), 5), 256, 0, stream>>>(
      x, xb, (int)(NE / 4), qw, wqb, kw, wkb, vw, wvb, (int)(WE / 4), fus_w, fwb,
      512 * 512 / 4);

  // projections for block 0 (-> set A) and blocks 1-3 (-> set B), one dispatch
  gemm_qkv6<<<dim3(4, 96, 6), 512, 0, stream>>>(xb, wqb, wkb, wvb, qb, kb, vb,
                                                Qb, Kb, Vb, Qc, Kc, Vc, 0);
  // attention block0 -> x_ (xres) and blocks1-3 -> raw concat (tl1), merged
  attn_merged<<<dim3(16, 32, 4), 512, 0, stream>>>(Qb, Kb, Vb, Qc, Kc, Vc, temp,
                                                   xres, tl1);
  // layernorm(tl1raw + x_) -> yb (fp16)
  ln_kernel<<<12288 / 4, 256, 0, stream>>>(tl1, xres, ln_g, ln_b, yb);
  // block 4 projections (set A reused)
  gemm_qkv6<<<dim3(4, 96, 3), 512, 0, stream>>>(yb, wqb, wkb, wvb, qb, kb, vb,
                                                Qb, Kb, Vb, Qb, Kb, Vb, 4);
  // block 4 attention: tl2 -> tl1 (in place), diff16 -> yb, diff32 -> xres
  attn_tail<<<dim3(16, 32, 1), 512, 0, stream>>>(Qb, Kb, Vb, temp + 64, xres, tl1,
                                                 yb, xres);
  // fusion: out = tl2 + diff32 * sigmoid(diff16 @ fus_w^T)
  gemm_fusion<<<dim3(4, 96), 512, 0, stream>>>(yb, fwb, xres, tl1, out);

  (void)in_sizes; (void)n_in; (void)out_size; (void)ws_size;
}

// Round 13
// 396.022 us; speedup vs baseline: 1.0814x; 1.0381x over previous
//
#include <hip/hip_runtime.h>

// ---------- types ----------
typedef __attribute__((ext_vector_type(8))) _Float16 half8;
typedef __attribute__((ext_vector_type(4))) _Float16 half4v;
typedef __attribute__((ext_vector_type(2))) _Float16 half2v;
typedef __attribute__((ext_vector_type(4))) float float4v;

// MFMA wrappers. Host pass chokes on top-level __has_builtin dispatch,
// so guard with __HIP_DEVICE_COMPILE__.
__device__ __forceinline__ float4v mfma16x16x32_f16(half8 a, half8 b, float4v c) {
#if defined(__HIP_DEVICE_COMPILE__)
#if __has_builtin(__builtin_amdgcn_mfma_f32_16x16x32_f16)
  return __builtin_amdgcn_mfma_f32_16x16x32_f16(a, b, c, 0, 0, 0);
#elif __has_builtin(__builtin_amdgcn_mfma_f32_16x16x32f16)
  return __builtin_amdgcn_mfma_f32_16x16x32f16(a, b, c, 0, 0, 0);
#else
#error "no 16x16x32 f16 mfma"
#endif
#else
  (void)a; (void)b;
  return c;
#endif
}

__device__ __forceinline__ float4v mfma16x16x16_f16(half4v a, half4v b, float4v c) {
#if defined(__HIP_DEVICE_COMPILE__)
#if __has_builtin(__builtin_amdgcn_mfma_f32_16x16x16f16)
  return __builtin_amdgcn_mfma_f32_16x16x16f16(a, b, c, 0, 0, 0);
#elif __has_builtin(__builtin_amdgcn_mfma_f32_16x16x16_f16)
  return __builtin_amdgcn_mfma_f32_16x16x16_f16(a, b, c, 0, 0, 0);
#else
#error "no 16x16x16 f16 mfma"
#endif
#else
  (void)a; (void)b;
  return c;
#endif
}

// async global->LDS, 16B per lane. LDS dest must be wave-uniform base + lane*16.
__device__ __forceinline__ void gl_lds16(const unsigned short* g, unsigned short* l) {
#if defined(__HIP_DEVICE_COMPILE__)
#if __has_builtin(__builtin_amdgcn_global_load_lds)
  __builtin_amdgcn_global_load_lds(
      (const __attribute__((address_space(1))) unsigned int*)g,
      (__attribute__((address_space(3))) unsigned int*)l, 16, 0, 0);
#else
  *(uint4*)l = *(const uint4*)g;
#endif
#else
  (void)g; (void)l;
#endif
}

__device__ __forceinline__ float fexp2(float x) {
#if defined(__HIP_DEVICE_COMPILE__)
#if __has_builtin(__builtin_amdgcn_exp2f)
  return __builtin_amdgcn_exp2f(x);
#else
  return __expf(x * 0.6931471805599453f);
#endif
#else
  return x;
#endif
}

__device__ __forceinline__ float frcp(float x) {
#if defined(__HIP_DEVICE_COMPILE__)
#if __has_builtin(__builtin_amdgcn_rcpf)
  return __builtin_amdgcn_rcpf(x);
#else
  return 1.0f / x;
#endif
#else
  return 1.0f / x;
#endif
}

__device__ __forceinline__ half2v pk_f16(float a, float b) {
#if defined(__HIP_DEVICE_COMPILE__)
#if __has_builtin(__builtin_amdgcn_cvt_pkrtz)
  return __builtin_bit_cast(half2v, __builtin_amdgcn_cvt_pkrtz(a, b));
#else
  half2v r;
  r[0] = (_Float16)a;
  r[1] = (_Float16)b;
  return r;
#endif
#else
  half2v r;
  r[0] = (_Float16)a;
  r[1] = (_Float16)b;
  return r;
#endif
}

// s_setprio needs a CONSTANT integer argument (round-10 compile failure:
// a runtime int parameter is rejected before inlining). Template param makes
// it a constant expression at the builtin call site.
template <int P>
__device__ __forceinline__ void setprio() {
#if defined(__HIP_DEVICE_COMPILE__)
#if __has_builtin(__builtin_amdgcn_s_setprio)
  __builtin_amdgcn_s_setprio(P);
#endif
#endif
}

__device__ __forceinline__ unsigned short f2h(float f) {
  union { _Float16 h; unsigned short u; } v;
  v.h = (_Float16)f;
  return v.u;
}

// 16-lane (DPP row_ror) rotation-butterfly sum: every lane of each 16-group
// ends with the group total. 4 full-rate VALU adds, no LDS-pipe latency.
__device__ __forceinline__ float row_sum16(float x) {
#if defined(__HIP_DEVICE_COMPILE__)
#if __has_builtin(__builtin_amdgcn_update_dpp)
  int v;
  v = __builtin_bit_cast(int, x);
  x += __builtin_bit_cast(float, __builtin_amdgcn_update_dpp(0, v, 0x128, 0xF, 0xF, true));
  v = __builtin_bit_cast(int, x);
  x += __builtin_bit_cast(float, __builtin_amdgcn_update_dpp(0, v, 0x124, 0xF, 0xF, true));
  v = __builtin_bit_cast(int, x);
  x += __builtin_bit_cast(float, __builtin_amdgcn_update_dpp(0, v, 0x122, 0xF, 0xF, true));
  v = __builtin_bit_cast(int, x);
  x += __builtin_bit_cast(float, __builtin_amdgcn_update_dpp(0, v, 0x121, 0xF, 0xF, true));
  return x;
#else
  x += __shfl_xor(x, 1);
  x += __shfl_xor(x, 2);
  x += __shfl_xor(x, 4);
  x += __shfl_xor(x, 8);
  return x;
#endif
#else
  return x;
#endif
}

// ---------- merged fp32 -> fp16 converts (5 tensors, one dispatch) ----------
__global__ __launch_bounds__(256) void cvt_multi(
    const float* __restrict__ s0, unsigned short* __restrict__ d0, int n0,
    const float* __restrict__ s1, unsigned short* __restrict__ d1,
    const float* __restrict__ s2, unsigned short* __restrict__ d2,
    const float* __restrict__ s3, unsigned short* __restrict__ d3, int n13,
    const float* __restrict__ s4, unsigned short* __restrict__ d4, int n4c) {
  const int y = blockIdx.y;
  const float* s;
  unsigned short* d;
  int n;
  if (y == 0) { s = s0; d = d0; n = n0; }
  else if (y == 1) { s = s1; d = d1; n = n13; }
  else if (y == 2) { s = s2; d = d2; n = n13; }
  else if (y == 3) { s = s3; d = d3; n = n13; }
  else { s = s4; d = d4; n = n4c; }
  const int i = blockIdx.x * 256 + threadIdx.x;
  if (i >= n) return;
  float4 v = ((const float4*)s)[i];
  uint2 o;
  o.x = (unsigned)f2h(v.x) | ((unsigned)f2h(v.y) << 16);
  o.y = (unsigned)f2h(v.z) | ((unsigned)f2h(v.w) << 16);
  ((uint2*)d)[i] = o;
}

// ---------- shared GEMM core: 128x128 tile, K=512, 512 threads (8 waves 4x2) ----------
// 128x128 @ 32 KB LDS -> 4 blocks/CU. XOR chunk swizzle: LDS slot (row r,
// chunk sc) holds global chunk sc^(r&7); reader of chunk c uses c^(row&7);
// row&7 == col&7 since wm/wn/i*16 = 0 mod 8.
#define GEMM_CORE(WGPTR)                                                               \
  for (int k0 = 0; k0 < 512; k0 += 64) {                                               \
    _Pragma("unroll") for (int rnd = 0; rnd < 2; ++rnd) {                              \
      const int slot = rnd * 512 + tid;                                                \
      const int r = slot >> 3;                                                         \
      const int c = (slot & 7) ^ (r & 7);                                              \
      gl_lds16(Xbase + xrow0 + (size_t)r * 512 + (size_t)(k0 + c * 8), &Xs[slot * 8]); \
    }                                                                                  \
    _Pragma("unroll") for (int rnd = 0; rnd < 2; ++rnd) {                              \
      const int s2 = rnd * 512 + tid;                                                  \
      const int r = s2 >> 3;                                                           \
      const int c = (s2 & 7) ^ (r & 7);                                                \
      gl_lds16((WGPTR) + (size_t)r * 512 + k0 + c * 8, &Wt[s2 * 8]);                   \
    }                                                                                  \
    __syncthreads();                                                                   \
    _Pragma("unroll") for (int kk = 0; kk < 2; ++kk) {                                 \
      half8 af[2], bf[4];                                                              \
      const int ch = ((kk * 4 + grp) ^ (col & 7)) * 8;                                 \
      _Pragma("unroll") for (int i = 0; i < 2; ++i)                                    \
          af[i] = *(const half8*)&Xs[(wm + i * 16 + col) * 64 + ch];                   \
      _Pragma("unroll") for (int j = 0; j < 4; ++j)                                    \
          bf[j] = *(const half8*)&Wt[(wn + j * 16 + col) * 64 + ch];                   \
      _Pragma("unroll") for (int i = 0; i < 2; ++i)                                    \
          _Pragma("unroll") for (int j = 0; j < 4; ++j)                                \
              acc[i][j] = mfma16x16x32_f16(af[i], bf[j], acc[i][j]);                   \
    }                                                                                  \
    __syncthreads();                                                                   \
  }

// ---------- QKV projection GEMM, dual-output-set ----------
// z in [0,6): zz=z%3 picks {q,k,v}; mode=z/3 picks output set and weight mode.
// mt in [0,96): batch = mt/3, cpart = mt%3 -> 128-row tile = one batch's one
// chunk part (widx-uniform for the chunked weight dispatch).
__global__ __launch_bounds__(512) void gemm_qkv6(
    const unsigned short* __restrict__ X,
    const unsigned short* __restrict__ Wq, const unsigned short* __restrict__ Wk,
    const unsigned short* __restrict__ Wv,
    const float* __restrict__ bq, const float* __restrict__ bk, const float* __restrict__ bv,
    unsigned short* __restrict__ CqA, unsigned short* __restrict__ CkA,
    unsigned short* __restrict__ CvA, unsigned short* __restrict__ CqB,
    unsigned short* __restrict__ CkB, unsigned short* __restrict__ CvB,
    int widx_fixed) {
  const int nt = blockIdx.x, mt = blockIdx.y, z = blockIdx.z;
  const int zz = z % 3, mode = z / 3;
  const unsigned short* W = (zz == 0) ? Wq : ((zz == 1) ? Wk : Wv);
  const float* bias = (zz == 0) ? bq : ((zz == 1) ? bk : bv);
  unsigned short* C = mode ? ((zz == 0) ? CqB : ((zz == 1) ? CkB : CvB))
                           : ((zz == 0) ? CqA : ((zz == 1) ? CkA : CvA));
  const int cpart = mt % 3, batch = mt / 3;
  const int widx = mode ? (1 + cpart) : widx_fixed;
  W += (size_t)widx * 512 * 512;
  bias += widx * 512;

  const size_t grow0 = (size_t)batch * 384 + cpart * 128;
  const size_t xrow0 = grow0 * 512;
  const unsigned short* Xbase = X;

  __shared__ __align__(16) unsigned short Xs[1024 * 8];  // 128x64 f16 (16 KB)
  __shared__ __align__(16) unsigned short Wt[1024 * 8];  // 128x64 f16 (16 KB)
  const int tid = threadIdx.x, lane = tid & 63, w = tid >> 6;
  const int col = lane & 15, grp = lane >> 4;
  const int wm = (w >> 1) * 32, wn = (w & 1) * 64;

  const float4v zero4 = {0.f, 0.f, 0.f, 0.f};
  float4v acc[2][4];
#pragma unroll
  for (int i = 0; i < 2; ++i)
#pragma unroll
    for (int j = 0; j < 4; ++j) acc[i][j] = zero4;

  GEMM_CORE(W + (size_t)nt * 128 * 512)

#pragma unroll
  for (int j = 0; j < 4; ++j) {
    const int n = nt * 128 + wn + j * 16 + col;
    const float bj = bias[n];
#pragma unroll
    for (int i = 0; i < 2; ++i)
#pragma unroll
      for (int r = 0; r < 4; ++r) {
        const int m = wm + i * 16 + grp * 4 + r;
        C[(grow0 + m) * 512 + n] = f2h(acc[i][j][r] + bj);
      }
  }
}

// ---------- fusion GEMM: z = diff16 @ W^T ; out = tl2 + diff32*sigmoid(z) ----------
__global__ __launch_bounds__(512) void gemm_fusion(
    const unsigned short* __restrict__ X, const unsigned short* __restrict__ Wf,
    const float* __restrict__ dif, const float* __restrict__ tl2, float* __restrict__ outp) {
  const int nt = blockIdx.x, mt = blockIdx.y;
  const size_t grow0 = (size_t)mt * 128;
  const size_t xrow0 = grow0 * 512;
  const unsigned short* Xbase = X;

  __shared__ __align__(16) unsigned short Xs[1024 * 8];
  __shared__ __align__(16) unsigned short Wt[1024 * 8];
  const int tid = threadIdx.x, lane = tid & 63, w = tid >> 6;
  const int col = lane & 15, grp = lane >> 4;
  const int wm = (w >> 1) * 32, wn = (w & 1) * 64;

  const float4v zero4 = {0.f, 0.f, 0.f, 0.f};
  float4v acc[2][4];
#pragma unroll
  for (int i = 0; i < 2; ++i)
#pragma unroll
    for (int j = 0; j < 4; ++j) acc[i][j] = zero4;

  GEMM_CORE(Wf + (size_t)nt * 128 * 512)

#pragma unroll
  for (int j = 0; j < 4; ++j) {
    const int n = nt * 128 + wn + j * 16 + col;
#pragma unroll
    for (int i = 0; i < 2; ++i)
#pragma unroll
      for (int r = 0; r < 4; ++r) {
        const int m = wm + i * 16 + grp * 4 + r;
        const size_t off = (grow0 + m) * 512 + n;
        const float d = dif[off], t2 = tl2[off];
        const float sg = 1.0f / (1.0f + __expf(-acc[i][j][r]));
        outp[off] = t2 + d * sg;
      }
  }
}

// ---------- attention body, two-pass recompute, 512 threads ----------
// Round-6 champion structure: 2 barriers/block, f32 exp (f16 exp OVERFLOWS:
// |S|~40 -> e~1e15, round-4 failure), LDS-atomic Z, unroll 2.
// PRIO (s_setprio around compute) and VFIRST (V reg-loads before K gather):
// both measured POSITIVE in attn_merged (mixed heavy/light phases; r11/r12:
// 138->130 us). attn_tail (512 lockstep co-resident blocks) gets the exact
// round-9 body (K-first, no prio) — r12's ledger showed ~+15 us there vs r9
// with V-first, isolating the last variable.
template <int T, bool PRIO, bool VFIRST>
__device__ __forceinline__ void attn_body(
    const unsigned short* __restrict__ Qb, const unsigned short* __restrict__ Kb,
    const unsigned short* __restrict__ Vb, const float* __restrict__ temp_base,
    const float* add_src,  // may alias diff32
    float* outp, int chunk_elems, int cb, int h, int b,
    const float* tl1_src,  // may alias outp (tail writes tl2 in place)
    unsigned short* diff16, float* diff32,
    unsigned short* KVt, float* Zs) {
  constexpr int NT = T / 16;
  constexpr int NSW = NT / 8;
  constexpr int SLAB = T * 32;
  const int base = b * (384 * 512) + cb * chunk_elems + h * SLAB;
  const float tl2e = temp_base[cb * 16 + h] * 1.4426950408889634f;

  const int tid = threadIdx.x, lane = tid & 63, w = tid >> 6;
  const int col = lane & 15, grp = lane >> 4;

  // zero the Z accumulators (covered by the staging barrier)
  if (tid < NT * 16) Zs[tid] = 0.f;

  half8 vfr[NSW];
  auto load_v = [&]() {
    const unsigned short* Vg = Vb + base;
#pragma unroll
    for (int si = 0; si < NSW; ++si) {
      const int s = (w + si * 8) * 16 + col;
      union { unsigned short u[8]; half8 v; } t8;
#pragma unroll
      for (int i = 0; i < 8; ++i) t8.u[i] = Vg[(size_t)(grp * 8 + i) * T + s];
      vfr[si] = t8.v;
    }
  };
  auto stage_k = [&]() {
    const unsigned short* src = Kb + base;
    constexpr int ITER = (T * 4) / 512;
#pragma unroll
    for (int p = 0; p < ITER; ++p) {
      const int f = p * 512 + tid;
      const int t = f >> 2, blk = (f & 3) * 8;
      unsigned short tmp[8];
#pragma unroll
      for (int i = 0; i < 8; ++i) tmp[i] = src[(size_t)(blk + i) * T + t];
      *(uint4*)&KVt[t * 40 + blk] = *(const uint4*)tmp;
    }
  };
  if constexpr (VFIRST) {
    load_v();
    stage_k();
  } else {
    stage_k();
    load_v();
  }
  __syncthreads();

  const float4v zero4 = {0.f, 0.f, 0.f, 0.f};

  // --- pass 1: full Z via LDS atomics ---
#pragma unroll 2
  for (int tt = 0; tt < NT; ++tt) {
    half8 kf = *(const half8*)&KVt[(tt * 16 + col) * 40 + grp * 8];
    float z0 = 0.f, z1 = 0.f, z2 = 0.f, z3 = 0.f;
    if constexpr (PRIO) setprio<1>();
#pragma unroll
    for (int si = 0; si < NSW; ++si) {
      float4v sv = mfma16x16x32_f16(kf, vfr[si], zero4);
      z0 += fexp2(sv[0] * tl2e);
      z1 += fexp2(sv[1] * tl2e);
      z2 += fexp2(sv[2] * tl2e);
      z3 += fexp2(sv[3] * tl2e);
    }
    if constexpr (PRIO) setprio<0>();
    z0 = row_sum16(z0);
    z1 = row_sum16(z1);
    z2 = row_sum16(z2);
    z3 = row_sum16(z3);
    if (col == 0) {
      float* zp = &Zs[tt * 16 + grp * 4];
      atomicAdd(zp + 0, z0);
      atomicAdd(zp + 1, z1);
      atomicAdd(zp + 2, z2);
      atomicAdd(zp + 3, z3);
    }
  }
  __syncthreads();

  // --- pass 2: recompute S, normalize, PV ---
  const unsigned short* Qsl = Qb + base;
  float4v oacc[NSW][2];
#pragma unroll
  for (int si = 0; si < NSW; ++si) {
    oacc[si][0] = zero4;
    oacc[si][1] = zero4;
  }
#pragma unroll 2
  for (int tt = 0; tt < NT; ++tt) {
    const int toff = tt * 16 + grp * 4;
    half4v qa0 = *(const half4v*)(Qsl + col * T + toff);
    half4v qa1 = *(const half4v*)(Qsl + (16 + col) * T + toff);
    float4v zsv = *(const float4v*)&Zs[tt * 16 + grp * 4];
    const float zi0 = frcp(zsv[0]), zi1 = frcp(zsv[1]), zi2 = frcp(zsv[2]),
                zi3 = frcp(zsv[3]);
    half8 kf = *(const half8*)&KVt[(tt * 16 + col) * 40 + grp * 8];
    if constexpr (PRIO) setprio<1>();
#pragma unroll
    for (int si = 0; si < NSW; ++si) {
      float4v sv = mfma16x16x32_f16(kf, vfr[si], zero4);
      half2v lo = pk_f16(fexp2(sv[0] * tl2e) * zi0, fexp2(sv[1] * tl2e) * zi1);
      half2v hi = pk_f16(fexp2(sv[2] * tl2e) * zi2, fexp2(sv[3] * tl2e) * zi3);
      half4v pb = __builtin_shufflevector(lo, hi, 0, 1, 2, 3);
      oacc[si][0] = mfma16x16x16_f16(qa0, pb, oacc[si][0]);
      oacc[si][1] = mfma16x16x16_f16(qa1, pb, oacc[si][1]);
    }
    if constexpr (PRIO) setprio<0>();
  }

  // --- epilogue ---
#pragma unroll
  for (int si = 0; si < NSW; ++si) {
    const int s = (w + si * 8) * 16 + col;
#pragma unroll
    for (int m0 = 0; m0 < 2; ++m0) {
#pragma unroll
      for (int r = 0; r < 4; ++r) {
        const int dd = m0 * 16 + grp * 4 + r;
        const int off = base + dd * T + s;
        const float o = oacc[si][m0][r];
        float v = o;
        if (add_src) v += add_src[off];
        if (tl1_src) {
          // diff = tl1_final - tl2 = (concat + x_) - (out4 + x_) = concat - out4
          const float d = tl1_src[off] - o;
          diff16[off] = f2h(d);
          diff32[off] = d;  // in-place over add_src[off]: read above precedes
        }
        outp[off] = v;  // in-place over tl1_src[off]: read above precedes
      }
    }
  }
}

// Merged attention: block0 (T=384) + blocks1-3 chunks (T=128) in one dispatch.
// 2048 blocks, heavy/light interleaved (id&3). LDS ~32.3 KB;
// no occupancy pin (round-1's (512,8) pin forced spills).
// PRIO=true + VFIRST=true: measured best (r12: 130 us, VGPR 36, occ 27%).
__global__ __launch_bounds__(512) void attn_merged(
    const unsigned short* __restrict__ Q0, const unsigned short* __restrict__ K0,
    const unsigned short* __restrict__ V0, const unsigned short* __restrict__ Qc,
    const unsigned short* __restrict__ Kc, const unsigned short* __restrict__ Vc,
    const float* __restrict__ temp, float* xres, float* tl1) {
  __shared__ __align__(16) unsigned short Ks[384 * 40];
  __shared__ __align__(16) float Zs[24 * 16];
  const int id = blockIdx.x + 16 * (blockIdx.y + 32 * blockIdx.z);
  const int part = id & 3, rest = id >> 2;
  const int h = rest & 15, b = rest >> 4;
  if (part == 0)
    attn_body<384, true, true>(Q0, K0, V0, temp, nullptr, xres, 0, 0, h, b,
                               nullptr, nullptr, nullptr, Ks, Zs);
  else
    attn_body<128, true, true>(Qc, Kc, Vc, temp + 16, nullptr, tl1, 128 * 512,
                               part - 1, h, b, nullptr, nullptr, nullptr, Ks, Zs);
}

// Tail attention (block 4): tl2 = out4 + x_ written in place into tl1 buffer,
// diff (f32 and f16) written; diff32 lands in place over x_ (add_src).
// PRIO=false + VFIRST=false: bit-exact round-9 body — 512 lockstep co-resident
// blocks are the regime where both micro-levers measured null-to-negative.
__global__ __launch_bounds__(512) void attn_tail(
    const unsigned short* __restrict__ Q, const unsigned short* __restrict__ K,
    const unsigned short* __restrict__ V, const float* __restrict__ temp4,
    const float* add_src, float* tl12, unsigned short* __restrict__ diff16,
    float* diff32) {
  __shared__ __align__(16) unsigned short Ks[384 * 40];
  __shared__ __align__(16) float Zs[24 * 16];
  attn_body<384, false, false>(Q, K, V, temp4, add_src, tl12, 0, 0, blockIdx.x,
                               blockIdx.y, tl12, diff16, diff32, Ks, Zs);
}

// ---------- layernorm over rows of 512 of (a + c) -> fp16 ----------
__global__ __launch_bounds__(256) void ln_kernel(const float* __restrict__ a,
                                                 const float* __restrict__ c,
                                                 const float* __restrict__ g,
                                                 const float* __restrict__ bb,
                                                 unsigned short* __restrict__ y) {
  const int row = blockIdx.x * 4 + (threadIdx.x >> 6);
  const int lane = threadIdx.x & 63;
  const float* ar = a + (size_t)row * 512;
  const float* cr = c + (size_t)row * 512;
  float4 a0 = *(const float4*)&ar[lane * 8];
  float4 a1 = *(const float4*)&ar[lane * 8 + 4];
  float4 c0 = *(const float4*)&cr[lane * 8];
  float4 c1 = *(const float4*)&cr[lane * 8 + 4];
  float4 v0, v1;
  v0.x = a0.x + c0.x; v0.y = a0.y + c0.y; v0.z = a0.z + c0.z; v0.w = a0.w + c0.w;
  v1.x = a1.x + c1.x; v1.y = a1.y + c1.y; v1.z = a1.z + c1.z; v1.w = a1.w + c1.w;
  float s = v0.x + v0.y + v0.z + v0.w + v1.x + v1.y + v1.z + v1.w;
  float q = v0.x * v0.x + v0.y * v0.y + v0.z * v0.z + v0.w * v0.w +
            v1.x * v1.x + v1.y * v1.y + v1.z * v1.z + v1.w * v1.w;
#pragma unroll
  for (int m = 1; m < 64; m <<= 1) {
    s += __shfl_xor(s, m);
    q += __shfl_xor(q, m);
  }
  const float mean = s * (1.0f / 512.0f);
  const float var = q * (1.0f / 512.0f) - mean * mean;
  const float rs = rsqrtf(var + 1e-5f);
  float4 g0 = *(const float4*)&g[lane * 8];
  float4 g1 = *(const float4*)&g[lane * 8 + 4];
  float4 b0 = *(const float4*)&bb[lane * 8];
  float4 b1 = *(const float4*)&bb[lane * 8 + 4];
  uint4 o;
  o.x = (unsigned)f2h((v0.x - mean) * rs * g0.x + b0.x) |
        ((unsigned)f2h((v0.y - mean) * rs * g0.y + b0.y) << 16);
  o.y = (unsigned)f2h((v0.z - mean) * rs * g0.z + b0.z) |
        ((unsigned)f2h((v0.w - mean) * rs * g0.w + b0.w) << 16);
  o.z = (unsigned)f2h((v1.x - mean) * rs * g1.x + b1.x) |
        ((unsigned)f2h((v1.y - mean) * rs * g1.y + b1.y) << 16);
  o.w = (unsigned)f2h((v1.z - mean) * rs * g1.z + b1.z) |
        ((unsigned)f2h((v1.w - mean) * rs * g1.w + b1.w) << 16);
  *(uint4*)&y[(size_t)row * 512 + lane * 8] = o;
}

// ---------- launch ----------
extern "C" void kernel_launch(void* const* d_in, const int* in_sizes, int n_in,
                              void* d_out, int out_size, void* d_ws, size_t ws_size,
                              hipStream_t stream) {
  const float* x = (const float*)d_in[0];
  const float* qw = (const float*)d_in[1];
  const float* qb = (const float*)d_in[2];
  const float* kw = (const float*)d_in[3];
  const float* kb = (const float*)d_in[4];
  const float* vw = (const float*)d_in[5];
  const float* vb = (const float*)d_in[6];
  const float* temp = (const float*)d_in[7];
  const float* ln_g = (const float*)d_in[8];
  const float* ln_b = (const float*)d_in[9];
  const float* fus_w = (const float*)d_in[10];
  // fus_b (d_in[11]) cancels in the 2-way softmax; num_heads (d_in[12]) fixed at 16
  float* out = (float*)d_out;

  const size_t NE = (size_t)32 * 384 * 512;  // 6291456
  const size_t WE = (size_t)5 * 512 * 512;   // 1310720

  char* p = (char*)d_ws;
  auto alloc = [&](size_t bytes) {
    char* r = p;
    p += (bytes + 255) & ~(size_t)255;
    return r;
  };
  unsigned short* xb = (unsigned short*)alloc(NE * 2);
  unsigned short* wqb = (unsigned short*)alloc(WE * 2);
  unsigned short* wkb = (unsigned short*)alloc(WE * 2);
  unsigned short* wvb = (unsigned short*)alloc(WE * 2);
  unsigned short* fwb = (unsigned short*)alloc((size_t)512 * 512 * 2);
  unsigned short* Qb = (unsigned short*)alloc(NE * 2);
  unsigned short* Kb = (unsigned short*)alloc(NE * 2);
  unsigned short* Vb = (unsigned short*)alloc(NE * 2);
  float* xres = (float*)alloc(NE * 4);  // x_ , later diff32 (in place)
  float* tl1 = (float*)alloc(NE * 4);   // raw concat, later tl2 (in place)
  unsigned short* yb = (unsigned short*)alloc(NE * 2);  // Qc, LN out, later diff16

  // chunk QKV scratch: Qc shares yb; Kc/Vc live in d_out (exactly 2*NE*2 B),
  // overwritten by the final fusion GEMM.
  unsigned short* Qc = yb;
  unsigned short* Kc = (unsigned short*)out;
  unsigned short* Vc = Kc + NE;

  // all converts in one dispatch
  cvt_multi<<<dim3((int)(NE / 4 / 256), 5), 256, 0, stream>>>(
      x, xb, (int)(NE / 4), qw, wqb, kw, wkb, vw, wvb, (int)(WE / 4), fus_w, fwb,
      512 * 512 / 4);

  // projections for block 0 (-> set A) and blocks 1-3 (-> set B), one dispatch
  gemm_qkv6<<<dim3(4, 96, 6), 512, 0, stream>>>(xb, wqb, wkb, wvb, qb, kb, vb,
                                                Qb, Kb, Vb, Qc, Kc, Vc, 0);
  // attention block0 -> x_ (xres) and blocks1-3 -> raw concat (tl1), merged
  attn_merged<<<dim3(16, 32, 4), 512, 0, stream>>>(Qb, Kb, Vb, Qc, Kc, Vc, temp,
                                                   xres, tl1);
  // layernorm(tl1raw + x_) -> yb (fp16)
  ln_kernel<<<12288 / 4, 256, 0, stream>>>(tl1, xres, ln_g, ln_b, yb);
  // block 4 projections (set A reused)
  gemm_qkv6<<<dim3(4, 96, 3), 512, 0, stream>>>(yb, wqb, wkb, wvb, qb, kb, vb,
                                                Qb, Kb, Vb, Qb, Kb, Vb, 4);
  // block 4 attention: tl2 -> tl1 (in place), diff16 -> yb, diff32 -> xres
  attn_tail<<<dim3(16, 32, 1), 512, 0, stream>>>(Qb, Kb, Vb, temp + 64, xres, tl1,
                                                 yb, xres);
  // fusion: out = tl2 + diff32 * sigmoid(diff16 @ fus_w^T)
  gemm_fusion<<<dim3(4, 96), 512, 0, stream>>>(yb, fwb, xres, tl1, out);

  (void)in_sizes; (void)n_in; (void)out_size; (void)ws_size;
}

// Round 14
// 355.720 us; speedup vs baseline: 1.2039x; 1.1133x over previous
//
#include <hip/hip_runtime.h>

// ---------- types ----------
typedef __attribute__((ext_vector_type(8))) _Float16 half8;
typedef __attribute__((ext_vector_type(4))) _Float16 half4v;
typedef __attribute__((ext_vector_type(2))) _Float16 half2v;
typedef __attribute__((ext_vector_type(4))) float float4v;

// MFMA wrappers. Host pass chokes on top-level __has_builtin dispatch,
// so guard with __HIP_DEVICE_COMPILE__.
__device__ __forceinline__ float4v mfma16x16x32_f16(half8 a, half8 b, float4v c) {
#if defined(__HIP_DEVICE_COMPILE__)
#if __has_builtin(__builtin_amdgcn_mfma_f32_16x16x32_f16)
  return __builtin_amdgcn_mfma_f32_16x16x32_f16(a, b, c, 0, 0, 0);
#elif __has_builtin(__builtin_amdgcn_mfma_f32_16x16x32f16)
  return __builtin_amdgcn_mfma_f32_16x16x32f16(a, b, c, 0, 0, 0);
#else
#error "no 16x16x32 f16 mfma"
#endif
#else
  (void)a; (void)b;
  return c;
#endif
}

__device__ __forceinline__ float4v mfma16x16x16_f16(half4v a, half4v b, float4v c) {
#if defined(__HIP_DEVICE_COMPILE__)
#if __has_builtin(__builtin_amdgcn_mfma_f32_16x16x16f16)
  return __builtin_amdgcn_mfma_f32_16x16x16f16(a, b, c, 0, 0, 0);
#elif __has_builtin(__builtin_amdgcn_mfma_f32_16x16x16_f16)
  return __builtin_amdgcn_mfma_f32_16x16x16_f16(a, b, c, 0, 0, 0);
#else
#error "no 16x16x16 f16 mfma"
#endif
#else
  (void)a; (void)b;
  return c;
#endif
}

// async global->LDS, 16B per lane. LDS dest must be wave-uniform base + lane*16.
__device__ __forceinline__ void gl_lds16(const unsigned short* g, unsigned short* l) {
#if defined(__HIP_DEVICE_COMPILE__)
#if __has_builtin(__builtin_amdgcn_global_load_lds)
  __builtin_amdgcn_global_load_lds(
      (const __attribute__((address_space(1))) unsigned int*)g,
      (__attribute__((address_space(3))) unsigned int*)l, 16, 0, 0);
#else
  *(uint4*)l = *(const uint4*)g;
#endif
#else
  (void)g; (void)l;
#endif
}

__device__ __forceinline__ float fexp2(float x) {
#if defined(__HIP_DEVICE_COMPILE__)
#if __has_builtin(__builtin_amdgcn_exp2f)
  return __builtin_amdgcn_exp2f(x);
#else
  return __expf(x * 0.6931471805599453f);
#endif
#else
  return x;
#endif
}

__device__ __forceinline__ float frcp(float x) {
#if defined(__HIP_DEVICE_COMPILE__)
#if __has_builtin(__builtin_amdgcn_rcpf)
  return __builtin_amdgcn_rcpf(x);
#else
  return 1.0f / x;
#endif
#else
  return 1.0f / x;
#endif
}

__device__ __forceinline__ half2v pk_f16(float a, float b) {
#if defined(__HIP_DEVICE_COMPILE__)
#if __has_builtin(__builtin_amdgcn_cvt_pkrtz)
  return __builtin_bit_cast(half2v, __builtin_amdgcn_cvt_pkrtz(a, b));
#else
  half2v r;
  r[0] = (_Float16)a;
  r[1] = (_Float16)b;
  return r;
#endif
#else
  half2v r;
  r[0] = (_Float16)a;
  r[1] = (_Float16)b;
  return r;
#endif
}

// s_setprio needs a CONSTANT integer argument (round-10 compile failure:
// a runtime int parameter is rejected before inlining). Template param makes
// it a constant expression at the builtin call site.
template <int P>
__device__ __forceinline__ void setprio() {
#if defined(__HIP_DEVICE_COMPILE__)
#if __has_builtin(__builtin_amdgcn_s_setprio)
  __builtin_amdgcn_s_setprio(P);
#endif
#endif
}

__device__ __forceinline__ unsigned short f2h(float f) {
  union { _Float16 h; unsigned short u; } v;
  v.h = (_Float16)f;
  return v.u;
}

// 16-lane (DPP row_ror) rotation-butterfly sum: every lane of each 16-group
// ends with the group total. 4 full-rate VALU adds, no LDS-pipe latency.
__device__ __forceinline__ float row_sum16(float x) {
#if defined(__HIP_DEVICE_COMPILE__)
#if __has_builtin(__builtin_amdgcn_update_dpp)
  int v;
  v = __builtin_bit_cast(int, x);
  x += __builtin_bit_cast(float, __builtin_amdgcn_update_dpp(0, v, 0x128, 0xF, 0xF, true));
  v = __builtin_bit_cast(int, x);
  x += __builtin_bit_cast(float, __builtin_amdgcn_update_dpp(0, v, 0x124, 0xF, 0xF, true));
  v = __builtin_bit_cast(int, x);
  x += __builtin_bit_cast(float, __builtin_amdgcn_update_dpp(0, v, 0x122, 0xF, 0xF, true));
  v = __builtin_bit_cast(int, x);
  x += __builtin_bit_cast(float, __builtin_amdgcn_update_dpp(0, v, 0x121, 0xF, 0xF, true));
  return x;
#else
  x += __shfl_xor(x, 1);
  x += __shfl_xor(x, 2);
  x += __shfl_xor(x, 4);
  x += __shfl_xor(x, 8);
  return x;
#endif
#else
  return x;
#endif
}

// ---------- merged fp32 -> fp16 converts (5 tensors, one dispatch) ----------
__global__ __launch_bounds__(256) void cvt_multi(
    const float* __restrict__ s0, unsigned short* __restrict__ d0, int n0,
    const float* __restrict__ s1, unsigned short* __restrict__ d1,
    const float* __restrict__ s2, unsigned short* __restrict__ d2,
    const float* __restrict__ s3, unsigned short* __restrict__ d3, int n13,
    const float* __restrict__ s4, unsigned short* __restrict__ d4, int n4c) {
  const int y = blockIdx.y;
  const float* s;
  unsigned short* d;
  int n;
  if (y == 0) { s = s0; d = d0; n = n0; }
  else if (y == 1) { s = s1; d = d1; n = n13; }
  else if (y == 2) { s = s2; d = d2; n = n13; }
  else if (y == 3) { s = s3; d = d3; n = n13; }
  else { s = s4; d = d4; n = n4c; }
  const int i = blockIdx.x * 256 + threadIdx.x;
  if (i >= n) return;
  float4 v = ((const float4*)s)[i];
  uint2 o;
  o.x = (unsigned)f2h(v.x) | ((unsigned)f2h(v.y) << 16);
  o.y = (unsigned)f2h(v.z) | ((unsigned)f2h(v.w) << 16);
  ((uint2*)d)[i] = o;
}

// ---------- shared GEMM core: 128x128 tile, K=512, 512 threads (8 waves 4x2) ----------
// 128x128 @ 32 KB LDS -> 4 blocks/CU. XOR chunk swizzle: LDS slot (row r,
// chunk sc) holds global chunk sc^(r&7); reader of chunk c uses c^(row&7);
// row&7 == col&7 since wm/wn/i*16 = 0 mod 8.
#define GEMM_CORE(WGPTR)                                                               \
  for (int k0 = 0; k0 < 512; k0 += 64) {                                               \
    _Pragma("unroll") for (int rnd = 0; rnd < 2; ++rnd) {                              \
      const int slot = rnd * 512 + tid;                                                \
      const int r = slot >> 3;                                                         \
      const int c = (slot & 7) ^ (r & 7);                                              \
      gl_lds16(Xbase + xrow0 + (size_t)r * 512 + (size_t)(k0 + c * 8), &Xs[slot * 8]); \
    }                                                                                  \
    _Pragma("unroll") for (int rnd = 0; rnd < 2; ++rnd) {                              \
      const int s2 = rnd * 512 + tid;                                                  \
      const int r = s2 >> 3;                                                           \
      const int c = (s2 & 7) ^ (r & 7);                                                \
      gl_lds16((WGPTR) + (size_t)r * 512 + k0 + c * 8, &Wt[s2 * 8]);                   \
    }                                                                                  \
    __syncthreads();                                                                   \
    _Pragma("unroll") for (int kk = 0; kk < 2; ++kk) {                                 \
      half8 af[2], bf[4];                                                              \
      const int ch = ((kk * 4 + grp) ^ (col & 7)) * 8;                                 \
      _Pragma("unroll") for (int i = 0; i < 2; ++i)                                    \
          af[i] = *(const half8*)&Xs[(wm + i * 16 + col) * 64 + ch];                   \
      _Pragma("unroll") for (int j = 0; j < 4; ++j)                                    \
          bf[j] = *(const half8*)&Wt[(wn + j * 16 + col) * 64 + ch];                   \
      _Pragma("unroll") for (int i = 0; i < 2; ++i)                                    \
          _Pragma("unroll") for (int j = 0; j < 4; ++j)                                \
              acc[i][j] = mfma16x16x32_f16(af[i], bf[j], acc[i][j]);                   \
    }                                                                                  \
    __syncthreads();                                                                   \
  }

// ---------- QKV projection GEMM, dual-output-set ----------
// z in [0,6): zz=z%3 picks {q,k,v}; mode=z/3 picks output set and weight mode.
// mt in [0,96): batch = mt/3, cpart = mt%3 -> 128-row tile = one batch's one
// chunk part (widx-uniform for the chunked weight dispatch).
__global__ __launch_bounds__(512) void gemm_qkv6(
    const unsigned short* __restrict__ X,
    const unsigned short* __restrict__ Wq, const unsigned short* __restrict__ Wk,
    const unsigned short* __restrict__ Wv,
    const float* __restrict__ bq, const float* __restrict__ bk, const float* __restrict__ bv,
    unsigned short* __restrict__ CqA, unsigned short* __restrict__ CkA,
    unsigned short* __restrict__ CvA, unsigned short* __restrict__ CqB,
    unsigned short* __restrict__ CkB, unsigned short* __restrict__ CvB,
    int widx_fixed) {
  const int nt = blockIdx.x, mt = blockIdx.y, z = blockIdx.z;
  const int zz = z % 3, mode = z / 3;
  const unsigned short* W = (zz == 0) ? Wq : ((zz == 1) ? Wk : Wv);
  const float* bias = (zz == 0) ? bq : ((zz == 1) ? bk : bv);
  unsigned short* C = mode ? ((zz == 0) ? CqB : ((zz == 1) ? CkB : CvB))
                           : ((zz == 0) ? CqA : ((zz == 1) ? CkA : CvA));
  const int cpart = mt % 3, batch = mt / 3;
  const int widx = mode ? (1 + cpart) : widx_fixed;
  W += (size_t)widx * 512 * 512;
  bias += widx * 512;

  const size_t grow0 = (size_t)batch * 384 + cpart * 128;
  const size_t xrow0 = grow0 * 512;
  const unsigned short* Xbase = X;

  __shared__ __align__(16) unsigned short Xs[1024 * 8];  // 128x64 f16 (16 KB)
  __shared__ __align__(16) unsigned short Wt[1024 * 8];  // 128x64 f16 (16 KB)
  const int tid = threadIdx.x, lane = tid & 63, w = tid >> 6;
  const int col = lane & 15, grp = lane >> 4;
  const int wm = (w >> 1) * 32, wn = (w & 1) * 64;

  const float4v zero4 = {0.f, 0.f, 0.f, 0.f};
  float4v acc[2][4];
#pragma unroll
  for (int i = 0; i < 2; ++i)
#pragma unroll
    for (int j = 0; j < 4; ++j) acc[i][j] = zero4;

  GEMM_CORE(W + (size_t)nt * 128 * 512)

#pragma unroll
  for (int j = 0; j < 4; ++j) {
    const int n = nt * 128 + wn + j * 16 + col;
    const float bj = bias[n];
#pragma unroll
    for (int i = 0; i < 2; ++i)
#pragma unroll
      for (int r = 0; r < 4; ++r) {
        const int m = wm + i * 16 + grp * 4 + r;
        C[(grow0 + m) * 512 + n] = f2h(acc[i][j][r] + bj);
      }
  }
}

// ---------- fusion GEMM: z = diff16 @ W^T ; out = tl2 + diff32*sigmoid(z) ----------
__global__ __launch_bounds__(512) void gemm_fusion(
    const unsigned short* __restrict__ X, const unsigned short* __restrict__ Wf,
    const float* __restrict__ dif, const float* __restrict__ tl2, float* __restrict__ outp) {
  const int nt = blockIdx.x, mt = blockIdx.y;
  const size_t grow0 = (size_t)mt * 128;
  const size_t xrow0 = grow0 * 512;
  const unsigned short* Xbase = X;

  __shared__ __align__(16) unsigned short Xs[1024 * 8];
  __shared__ __align__(16) unsigned short Wt[1024 * 8];
  const int tid = threadIdx.x, lane = tid & 63, w = tid >> 6;
  const int col = lane & 15, grp = lane >> 4;
  const int wm = (w >> 1) * 32, wn = (w & 1) * 64;

  const float4v zero4 = {0.f, 0.f, 0.f, 0.f};
  float4v acc[2][4];
#pragma unroll
  for (int i = 0; i < 2; ++i)
#pragma unroll
    for (int j = 0; j < 4; ++j) acc[i][j] = zero4;

  GEMM_CORE(Wf + (size_t)nt * 128 * 512)

#pragma unroll
  for (int j = 0; j < 4; ++j) {
    const int n = nt * 128 + wn + j * 16 + col;
#pragma unroll
    for (int i = 0; i < 2; ++i)
#pragma unroll
      for (int r = 0; r < 4; ++r) {
        const int m = wm + i * 16 + grp * 4 + r;
        const size_t off = (grow0 + m) * 512 + n;
        const float d = dif[off], t2 = tl2[off];
        const float sg = 1.0f / (1.0f + __expf(-acc[i][j][r]));
        outp[off] = t2 + d * sg;
      }
  }
}

// ---------- attention body, two-pass recompute, 512 threads ----------
// Round-6 champion structure: 2 barriers/block, f32 exp (f16 exp OVERFLOWS:
// |S|~40 -> e~1e15, round-4 failure), LDS-atomic Z, unroll 2.
// PRIO (s_setprio around compute) and VFIRST (V reg-loads before K gather):
// both measured POSITIVE in attn_merged (mixed-phase blocks; r11-r13:
// 138->130 us). attn_tail (512 lockstep co-resident blocks) uses the exact
// round-9 body (K-first, no prio) — r13 confirmed V-first/prio regress there.
template <int T, bool PRIO, bool VFIRST>
__device__ __forceinline__ void attn_body(
    const unsigned short* __restrict__ Qb, const unsigned short* __restrict__ Kb,
    const unsigned short* __restrict__ Vb, const float* __restrict__ temp_base,
    const float* add_src,  // may alias diff32
    float* outp, int chunk_elems, int cb, int h, int b,
    const float* tl1_src,  // may alias outp (tail writes tl2 in place)
    unsigned short* diff16, float* diff32,
    unsigned short* KVt, float* Zs) {
  constexpr int NT = T / 16;
  constexpr int NSW = NT / 8;
  constexpr int SLAB = T * 32;
  const int base = b * (384 * 512) + cb * chunk_elems + h * SLAB;
  const float tl2e = temp_base[cb * 16 + h] * 1.4426950408889634f;

  const int tid = threadIdx.x, lane = tid & 63, w = tid >> 6;
  const int col = lane & 15, grp = lane >> 4;

  // zero the Z accumulators (covered by the staging barrier)
  if (tid < NT * 16) Zs[tid] = 0.f;

  half8 vfr[NSW];
  auto load_v = [&]() {
    const unsigned short* Vg = Vb + base;
#pragma unroll
    for (int si = 0; si < NSW; ++si) {
      const int s = (w + si * 8) * 16 + col;
      union { unsigned short u[8]; half8 v; } t8;
#pragma unroll
      for (int i = 0; i < 8; ++i) t8.u[i] = Vg[(size_t)(grp * 8 + i) * T + s];
      vfr[si] = t8.v;
    }
  };
  auto stage_k = [&]() {
    const unsigned short* src = Kb + base;
    constexpr int ITER = (T * 4) / 512;
#pragma unroll
    for (int p = 0; p < ITER; ++p) {
      const int f = p * 512 + tid;
      const int t = f >> 2, blk = (f & 3) * 8;
      unsigned short tmp[8];
#pragma unroll
      for (int i = 0; i < 8; ++i) tmp[i] = src[(size_t)(blk + i) * T + t];
      *(uint4*)&KVt[t * 40 + blk] = *(const uint4*)tmp;
    }
  };
  if constexpr (VFIRST) {
    load_v();
    stage_k();
  } else {
    stage_k();
    load_v();
  }
  __syncthreads();

  const float4v zero4 = {0.f, 0.f, 0.f, 0.f};

  // --- pass 1: full Z via LDS atomics ---
#pragma unroll 2
  for (int tt = 0; tt < NT; ++tt) {
    half8 kf = *(const half8*)&KVt[(tt * 16 + col) * 40 + grp * 8];
    float z0 = 0.f, z1 = 0.f, z2 = 0.f, z3 = 0.f;
    if constexpr (PRIO) setprio<1>();
#pragma unroll
    for (int si = 0; si < NSW; ++si) {
      float4v sv = mfma16x16x32_f16(kf, vfr[si], zero4);
      z0 += fexp2(sv[0] * tl2e);
      z1 += fexp2(sv[1] * tl2e);
      z2 += fexp2(sv[2] * tl2e);
      z3 += fexp2(sv[3] * tl2e);
    }
    if constexpr (PRIO) setprio<0>();
    z0 = row_sum16(z0);
    z1 = row_sum16(z1);
    z2 = row_sum16(z2);
    z3 = row_sum16(z3);
    if (col == 0) {
      float* zp = &Zs[tt * 16 + grp * 4];
      atomicAdd(zp + 0, z0);
      atomicAdd(zp + 1, z1);
      atomicAdd(zp + 2, z2);
      atomicAdd(zp + 3, z3);
    }
  }
  __syncthreads();

  // --- pass 2: recompute S, normalize, PV ---
  const unsigned short* Qsl = Qb + base;
  float4v oacc[NSW][2];
#pragma unroll
  for (int si = 0; si < NSW; ++si) {
    oacc[si][0] = zero4;
    oacc[si][1] = zero4;
  }
#pragma unroll 2
  for (int tt = 0; tt < NT; ++tt) {
    const int toff = tt * 16 + grp * 4;
    half4v qa0 = *(const half4v*)(Qsl + col * T + toff);
    half4v qa1 = *(const half4v*)(Qsl + (16 + col) * T + toff);
    float4v zsv = *(const float4v*)&Zs[tt * 16 + grp * 4];
    const float zi0 = frcp(zsv[0]), zi1 = frcp(zsv[1]), zi2 = frcp(zsv[2]),
                zi3 = frcp(zsv[3]);
    half8 kf = *(const half8*)&KVt[(tt * 16 + col) * 40 + grp * 8];
    if constexpr (PRIO) setprio<1>();
#pragma unroll
    for (int si = 0; si < NSW; ++si) {
      float4v sv = mfma16x16x32_f16(kf, vfr[si], zero4);
      half2v lo = pk_f16(fexp2(sv[0] * tl2e) * zi0, fexp2(sv[1] * tl2e) * zi1);
      half2v hi = pk_f16(fexp2(sv[2] * tl2e) * zi2, fexp2(sv[3] * tl2e) * zi3);
      half4v pb = __builtin_shufflevector(lo, hi, 0, 1, 2, 3);
      oacc[si][0] = mfma16x16x16_f16(qa0, pb, oacc[si][0]);
      oacc[si][1] = mfma16x16x16_f16(qa1, pb, oacc[si][1]);
    }
    if constexpr (PRIO) setprio<0>();
  }

  // --- epilogue ---
#pragma unroll
  for (int si = 0; si < NSW; ++si) {
    const int s = (w + si * 8) * 16 + col;
#pragma unroll
    for (int m0 = 0; m0 < 2; ++m0) {
#pragma unroll
      for (int r = 0; r < 4; ++r) {
        const int dd = m0 * 16 + grp * 4 + r;
        const int off = base + dd * T + s;
        const float o = oacc[si][m0][r];
        float v = o;
        if (add_src) v += add_src[off];
        if (tl1_src) {
          // diff = tl1_final - tl2 = (concat + x_) - (out4 + x_) = concat - out4
          const float d = tl1_src[off] - o;
          diff16[off] = f2h(d);
          diff32[off] = d;  // in-place over add_src[off]: read above precedes
        }
        outp[off] = v;  // in-place over tl1_src[off]: read above precedes
      }
    }
  }
}

// Merged attention: block0 (T=384) + blocks1-3 chunks (T=128) in one dispatch.
// 2048 blocks. HEAVY-FIRST ordering (longest-processing-time scheduling):
// heavy blocks (~3x light work) occupy ids 0..511 so they launch first and
// light blocks backfill; the dispatch tail is then a LIGHT block's latency
// instead of a heavy one's (the r13 counters' 27% avg occupancy is consistent
// with a long low-occupancy heavy drain under the old id&3 interleave).
// LDS ~32.3 KB; no occupancy pin. PRIO=true + VFIRST=true (measured best).
__global__ __launch_bounds__(512) void attn_merged(
    const unsigned short* __restrict__ Q0, const unsigned short* __restrict__ K0,
    const unsigned short* __restrict__ V0, const unsigned short* __restrict__ Qc,
    const unsigned short* __restrict__ Kc, const unsigned short* __restrict__ Vc,
    const float* __restrict__ temp, float* xres, float* tl1) {
  __shared__ __align__(16) unsigned short Ks[384 * 40];
  __shared__ __align__(16) float Zs[24 * 16];
  const int id = blockIdx.x + 16 * (blockIdx.y + 32 * blockIdx.z);
  if (id < 512) {
    const int h = id & 15, b = id >> 4;
    attn_body<384, true, true>(Q0, K0, V0, temp, nullptr, xres, 0, 0, h, b,
                               nullptr, nullptr, nullptr, Ks, Zs);
  } else {
    const int idl = id - 512;
    const int cb = idl >> 9;       // 0..2 (512 blocks per chunk part)
    const int rest = idl & 511;
    const int h = rest & 15, b = rest >> 4;
    attn_body<128, true, true>(Qc, Kc, Vc, temp + 16, nullptr, tl1, 128 * 512,
                               cb, h, b, nullptr, nullptr, nullptr, Ks, Zs);
  }
}

// Tail attention (block 4): tl2 = out4 + x_ written in place into tl1 buffer,
// diff (f32 and f16) written; diff32 lands in place over x_ (add_src).
// PRIO=false + VFIRST=false: bit-exact round-9 body — 512 lockstep co-resident
// blocks are the regime where both micro-levers measured negative (r11-r13).
__global__ __launch_bounds__(512) void attn_tail(
    const unsigned short* __restrict__ Q, const unsigned short* __restrict__ K,
    const unsigned short* __restrict__ V, const float* __restrict__ temp4,
    const float* add_src, float* tl12, unsigned short* __restrict__ diff16,
    float* diff32) {
  __shared__ __align__(16) unsigned short Ks[384 * 40];
  __shared__ __align__(16) float Zs[24 * 16];
  attn_body<384, false, false>(Q, K, V, temp4, add_src, tl12, 0, 0, blockIdx.x,
                               blockIdx.y, tl12, diff16, diff32, Ks, Zs);
}

// ---------- layernorm over rows of 512 of (a + c) -> fp16 ----------
__global__ __launch_bounds__(256) void ln_kernel(const float* __restrict__ a,
                                                 const float* __restrict__ c,
                                                 const float* __restrict__ g,
                                                 const float* __restrict__ bb,
                                                 unsigned short* __restrict__ y) {
  const int row = blockIdx.x * 4 + (threadIdx.x >> 6);
  const int lane = threadIdx.x & 63;
  const float* ar = a + (size_t)row * 512;
  const float* cr = c + (size_t)row * 512;
  float4 a0 = *(const float4*)&ar[lane * 8];
  float4 a1 = *(const float4*)&ar[lane * 8 + 4];
  float4 c0 = *(const float4*)&cr[lane * 8];
  float4 c1 = *(const float4*)&cr[lane * 8 + 4];
  float4 v0, v1;
  v0.x = a0.x + c0.x; v0.y = a0.y + c0.y; v0.z = a0.z + c0.z; v0.w = a0.w + c0.w;
  v1.x = a1.x + c1.x; v1.y = a1.y + c1.y; v1.z = a1.z + c1.z; v1.w = a1.w + c1.w;
  float s = v0.x + v0.y + v0.z + v0.w + v1.x + v1.y + v1.z + v1.w;
  float q = v0.x * v0.x + v0.y * v0.y + v0.z * v0.z + v0.w * v0.w +
            v1.x * v1.x + v1.y * v1.y + v1.z * v1.z + v1.w * v1.w;
#pragma unroll
  for (int m = 1; m < 64; m <<= 1) {
    s += __shfl_xor(s, m);
    q += __shfl_xor(q, m);
  }
  const float mean = s * (1.0f / 512.0f);
  const float var = q * (1.0f / 512.0f) - mean * mean;
  const float rs = rsqrtf(var + 1e-5f);
  float4 g0 = *(const float4*)&g[lane * 8];
  float4 g1 = *(const float4*)&g[lane * 8 + 4];
  float4 b0 = *(const float4*)&bb[lane * 8];
  float4 b1 = *(const float4*)&bb[lane * 8 + 4];
  uint4 o;
  o.x = (unsigned)f2h((v0.x - mean) * rs * g0.x + b0.x) |
        ((unsigned)f2h((v0.y - mean) * rs * g0.y + b0.y) << 16);
  o.y = (unsigned)f2h((v0.z - mean) * rs * g0.z + b0.z) |
        ((unsigned)f2h((v0.w - mean) * rs * g0.w + b0.w) << 16);
  o.z = (unsigned)f2h((v1.x - mean) * rs * g1.x + b1.x) |
        ((unsigned)f2h((v1.y - mean) * rs * g1.y + b1.y) << 16);
  o.w = (unsigned)f2h((v1.z - mean) * rs * g1.z + b1.z) |
        ((unsigned)f2h((v1.w - mean) * rs * g1.w + b1.w) << 16);
  *(uint4*)&y[(size_t)row * 512 + lane * 8] = o;
}

// ---------- launch ----------
extern "C" void kernel_launch(void* const* d_in, const int* in_sizes, int n_in,
                              void* d_out, int out_size, void* d_ws, size_t ws_size,
                              hipStream_t stream) {
  const float* x = (const float*)d_in[0];
  const float* qw = (const float*)d_in[1];
  const float* qb = (const float*)d_in[2];
  const float* kw = (const float*)d_in[3];
  const float* kb = (const float*)d_in[4];
  const float* vw = (const float*)d_in[5];
  const float* vb = (const float*)d_in[6];
  const float* temp = (const float*)d_in[7];
  const float* ln_g = (const float*)d_in[8];
  const float* ln_b = (const float*)d_in[9];
  const float* fus_w = (const float*)d_in[10];
  // fus_b (d_in[11]) cancels in the 2-way softmax; num_heads (d_in[12]) fixed at 16
  float* out = (float*)d_out;

  const size_t NE = (size_t)32 * 384 * 512;  // 6291456
  const size_t WE = (size_t)5 * 512 * 512;   // 1310720

  char* p = (char*)d_ws;
  auto alloc = [&](size_t bytes) {
    char* r = p;
    p += (bytes + 255) & ~(size_t)255;
    return r;
  };
  unsigned short* xb = (unsigned short*)alloc(NE * 2);
  unsigned short* wqb = (unsigned short*)alloc(WE * 2);
  unsigned short* wkb = (unsigned short*)alloc(WE * 2);
  unsigned short* wvb = (unsigned short*)alloc(WE * 2);
  unsigned short* fwb = (unsigned short*)alloc((size_t)512 * 512 * 2);
  unsigned short* Qb = (unsigned short*)alloc(NE * 2);
  unsigned short* Kb = (unsigned short*)alloc(NE * 2);
  unsigned short* Vb = (unsigned short*)alloc(NE * 2);
  float* xres = (float*)alloc(NE * 4);  // x_ , later diff32 (in place)
  float* tl1 = (float*)alloc(NE * 4);   // raw concat, later tl2 (in place)
  unsigned short* yb = (unsigned short*)alloc(NE * 2);  // Qc, LN out, later diff16

  // chunk QKV scratch: Qc shares yb; Kc/Vc live in d_out (exactly 2*NE*2 B),
  // overwritten by the final fusion GEMM.
  unsigned short* Qc = yb;
  unsigned short* Kc = (unsigned short*)out;
  unsigned short* Vc = Kc + NE;

  // all converts in one dispatch
  cvt_multi<<<dim3((int)(NE / 4 / 256), 5), 256, 0, stream>>>(
      x, xb, (int)(NE / 4), qw, wqb, kw, wkb, vw, wvb, (int)(WE / 4), fus_w, fwb,
      512 * 512 / 4);

  // projections for block 0 (-> set A) and blocks 1-3 (-> set B), one dispatch
  gemm_qkv6<<<dim3(4, 96, 6), 512, 0, stream>>>(xb, wqb, wkb, wvb, qb, kb, vb,
                                                Qb, Kb, Vb, Qc, Kc, Vc, 0);
  // attention block0 -> x_ (xres) and blocks1-3 -> raw concat (tl1), merged
  attn_merged<<<dim3(16, 32, 4), 512, 0, stream>>>(Qb, Kb, Vb, Qc, Kc, Vc, temp,
                                                   xres, tl1);
  // layernorm(tl1raw + x_) -> yb (fp16)
  ln_kernel<<<12288 / 4, 256, 0, stream>>>(tl1, xres, ln_g, ln_b, yb);
  // block 4 projections (set A reused)
  gemm_qkv6<<<dim3(4, 96, 3), 512, 0, stream>>>(yb, wqb, wkb, wvb, qb, kb, vb,
                                                Qb, Kb, Vb, Qb, Kb, Vb, 4);
  // block 4 attention: tl2 -> tl1 (in place), diff16 -> yb, diff32 -> xres
  attn_tail<<<dim3(16, 32, 1), 512, 0, stream>>>(Qb, Kb, Vb, temp + 64, xres, tl1,
                                                 yb, xres);
  // fusion: out = tl2 + diff32 * sigmoid(diff16 @ fus_w^T)
  gemm_fusion<<<dim3(4, 96), 512, 0, stream>>>(yb, fwb, xres, tl1, out);

  (void)in_sizes; (void)n_in; (void)out_size; (void)ws_size;
}

// Round 15
// 334.838 us; speedup vs baseline: 1.2789x; 1.0624x over previous
//
#include <hip/hip_runtime.h>

// ---------- types ----------
typedef __attribute__((ext_vector_type(8))) _Float16 half8;
typedef __attribute__((ext_vector_type(4))) _Float16 half4v;
typedef __attribute__((ext_vector_type(2))) _Float16 half2v;
typedef __attribute__((ext_vector_type(4))) float float4v;

// MFMA wrappers. Host pass chokes on top-level __has_builtin dispatch,
// so guard with __HIP_DEVICE_COMPILE__.
__device__ __forceinline__ float4v mfma16x16x32_f16(half8 a, half8 b, float4v c) {
#if defined(__HIP_DEVICE_COMPILE__)
#if __has_builtin(__builtin_amdgcn_mfma_f32_16x16x32_f16)
  return __builtin_amdgcn_mfma_f32_16x16x32_f16(a, b, c, 0, 0, 0);
#elif __has_builtin(__builtin_amdgcn_mfma_f32_16x16x32f16)
  return __builtin_amdgcn_mfma_f32_16x16x32f16(a, b, c, 0, 0, 0);
#else
#error "no 16x16x32 f16 mfma"
#endif
#else
  (void)a; (void)b;
  return c;
#endif
}

__device__ __forceinline__ float4v mfma16x16x16_f16(half4v a, half4v b, float4v c) {
#if defined(__HIP_DEVICE_COMPILE__)
#if __has_builtin(__builtin_amdgcn_mfma_f32_16x16x16f16)
  return __builtin_amdgcn_mfma_f32_16x16x16f16(a, b, c, 0, 0, 0);
#elif __has_builtin(__builtin_amdgcn_mfma_f32_16x16x16_f16)
  return __builtin_amdgcn_mfma_f32_16x16x16_f16(a, b, c, 0, 0, 0);
#else
#error "no 16x16x16 f16 mfma"
#endif
#else
  (void)a; (void)b;
  return c;
#endif
}

// async global->LDS, 16B per lane. LDS dest must be wave-uniform base + lane*16.
__device__ __forceinline__ void gl_lds16(const unsigned short* g, unsigned short* l) {
#if defined(__HIP_DEVICE_COMPILE__)
#if __has_builtin(__builtin_amdgcn_global_load_lds)
  __builtin_amdgcn_global_load_lds(
      (const __attribute__((address_space(1))) unsigned int*)g,
      (__attribute__((address_space(3))) unsigned int*)l, 16, 0, 0);
#else
  *(uint4*)l = *(const uint4*)g;
#endif
#else
  (void)g; (void)l;
#endif
}

__device__ __forceinline__ float fexp2(float x) {
#if defined(__HIP_DEVICE_COMPILE__)
#if __has_builtin(__builtin_amdgcn_exp2f)
  return __builtin_amdgcn_exp2f(x);
#else
  return __expf(x * 0.6931471805599453f);
#endif
#else
  return x;
#endif
}

__device__ __forceinline__ float frcp(float x) {
#if defined(__HIP_DEVICE_COMPILE__)
#if __has_builtin(__builtin_amdgcn_rcpf)
  return __builtin_amdgcn_rcpf(x);
#else
  return 1.0f / x;
#endif
#else
  return 1.0f / x;
#endif
}

__device__ __forceinline__ half2v pk_f16(float a, float b) {
#if defined(__HIP_DEVICE_COMPILE__)
#if __has_builtin(__builtin_amdgcn_cvt_pkrtz)
  return __builtin_bit_cast(half2v, __builtin_amdgcn_cvt_pkrtz(a, b));
#else
  half2v r;
  r[0] = (_Float16)a;
  r[1] = (_Float16)b;
  return r;
#endif
#else
  half2v r;
  r[0] = (_Float16)a;
  r[1] = (_Float16)b;
  return r;
#endif
}

// s_setprio needs a CONSTANT integer argument (round-10 compile failure:
// a runtime int parameter is rejected before inlining). Template param makes
// it a constant expression at the builtin call site.
template <int P>
__device__ __forceinline__ void setprio() {
#if defined(__HIP_DEVICE_COMPILE__)
#if __has_builtin(__builtin_amdgcn_s_setprio)
  __builtin_amdgcn_s_setprio(P);
#endif
#endif
}

__device__ __forceinline__ unsigned short f2h(float f) {
  union { _Float16 h; unsigned short u; } v;
  v.h = (_Float16)f;
  return v.u;
}

// 16-lane (DPP row_ror) rotation-butterfly sum: every lane of each 16-group
// ends with the group total. 4 full-rate VALU adds, no LDS-pipe latency.
__device__ __forceinline__ float row_sum16(float x) {
#if defined(__HIP_DEVICE_COMPILE__)
#if __has_builtin(__builtin_amdgcn_update_dpp)
  int v;
  v = __builtin_bit_cast(int, x);
  x += __builtin_bit_cast(float, __builtin_amdgcn_update_dpp(0, v, 0x128, 0xF, 0xF, true));
  v = __builtin_bit_cast(int, x);
  x += __builtin_bit_cast(float, __builtin_amdgcn_update_dpp(0, v, 0x124, 0xF, 0xF, true));
  v = __builtin_bit_cast(int, x);
  x += __builtin_bit_cast(float, __builtin_amdgcn_update_dpp(0, v, 0x122, 0xF, 0xF, true));
  v = __builtin_bit_cast(int, x);
  x += __builtin_bit_cast(float, __builtin_amdgcn_update_dpp(0, v, 0x121, 0xF, 0xF, true));
  return x;
#else
  x += __shfl_xor(x, 1);
  x += __shfl_xor(x, 2);
  x += __shfl_xor(x, 4);
  x += __shfl_xor(x, 8);
  return x;
#endif
#else
  return x;
#endif
}

// ---------- merged fp32 -> fp16 converts (5 tensors, one dispatch) ----------
__global__ __launch_bounds__(256) void cvt_multi(
    const float* __restrict__ s0, unsigned short* __restrict__ d0, int n0,
    const float* __restrict__ s1, unsigned short* __restrict__ d1,
    const float* __restrict__ s2, unsigned short* __restrict__ d2,
    const float* __restrict__ s3, unsigned short* __restrict__ d3, int n13,
    const float* __restrict__ s4, unsigned short* __restrict__ d4, int n4c) {
  const int y = blockIdx.y;
  const float* s;
  unsigned short* d;
  int n;
  if (y == 0) { s = s0; d = d0; n = n0; }
  else if (y == 1) { s = s1; d = d1; n = n13; }
  else if (y == 2) { s = s2; d = d2; n = n13; }
  else if (y == 3) { s = s3; d = d3; n = n13; }
  else { s = s4; d = d4; n = n4c; }
  const int i = blockIdx.x * 256 + threadIdx.x;
  if (i >= n) return;
  float4 v = ((const float4*)s)[i];
  uint2 o;
  o.x = (unsigned)f2h(v.x) | ((unsigned)f2h(v.y) << 16);
  o.y = (unsigned)f2h(v.z) | ((unsigned)f2h(v.w) << 16);
  ((uint2*)d)[i] = o;
}

// ---------- shared GEMM core: 128x128 tile, K=512, 512 threads (8 waves 4x2) ----------
// 128x128 @ 32 KB LDS -> 4 blocks/CU. XOR chunk swizzle: LDS slot (row r,
// chunk sc) holds global chunk sc^(r&7); reader of chunk c uses c^(row&7);
// row&7 == col&7 since wm/wn/i*16 = 0 mod 8.
#define GEMM_CORE(WGPTR)                                                               \
  for (int k0 = 0; k0 < 512; k0 += 64) {                                               \
    _Pragma("unroll") for (int rnd = 0; rnd < 2; ++rnd) {                              \
      const int slot = rnd * 512 + tid;                                                \
      const int r = slot >> 3;                                                         \
      const int c = (slot & 7) ^ (r & 7);                                              \
      gl_lds16(Xbase + xrow0 + (size_t)r * 512 + (size_t)(k0 + c * 8), &Xs[slot * 8]); \
    }                                                                                  \
    _Pragma("unroll") for (int rnd = 0; rnd < 2; ++rnd) {                              \
      const int s2 = rnd * 512 + tid;                                                  \
      const int r = s2 >> 3;                                                           \
      const int c = (s2 & 7) ^ (r & 7);                                                \
      gl_lds16((WGPTR) + (size_t)r * 512 + k0 + c * 8, &Wt[s2 * 8]);                   \
    }                                                                                  \
    __syncthreads();                                                                   \
    _Pragma("unroll") for (int kk = 0; kk < 2; ++kk) {                                 \
      half8 af[2], bf[4];                                                              \
      const int ch = ((kk * 4 + grp) ^ (col & 7)) * 8;                                 \
      _Pragma("unroll") for (int i = 0; i < 2; ++i)                                    \
          af[i] = *(const half8*)&Xs[(wm + i * 16 + col) * 64 + ch];                   \
      _Pragma("unroll") for (int j = 0; j < 4; ++j)                                    \
          bf[j] = *(const half8*)&Wt[(wn + j * 16 + col) * 64 + ch];                   \
      _Pragma("unroll") for (int i = 0; i < 2; ++i)                                    \
          _Pragma("unroll") for (int j = 0; j < 4; ++j)                                \
              acc[i][j] = mfma16x16x32_f16(af[i], bf[j], acc[i][j]);                   \
    }                                                                                  \
    __syncthreads();                                                                   \
  }

// ---------- QKV projection GEMM, dual-output-set ----------
// XCD-locality grid: blockIdx.x = mt (96 values), blockIdx.y = nt (4).
// Linear id = mt + 96*(nt + 4*z); 96 % 8 == 0 and 384 % 8 == 0, so
// id % 8 == mt % 8: ALL 24 blocks (4 nt x 6 z) sharing one X 128-row tile
// land on the SAME XCD -> X tile is fetched into one L2 instead of all 8.
// Per-XCD X working set = 12 tiles x 128 KB = 1.5 MB (L2-resident).
__global__ __launch_bounds__(512) void gemm_qkv6(
    const unsigned short* __restrict__ X,
    const unsigned short* __restrict__ Wq, const unsigned short* __restrict__ Wk,
    const unsigned short* __restrict__ Wv,
    const float* __restrict__ bq, const float* __restrict__ bk, const float* __restrict__ bv,
    unsigned short* __restrict__ CqA, unsigned short* __restrict__ CkA,
    unsigned short* __restrict__ CvA, unsigned short* __restrict__ CqB,
    unsigned short* __restrict__ CkB, unsigned short* __restrict__ CvB,
    int widx_fixed) {
  const int mt = blockIdx.x, nt = blockIdx.y, z = blockIdx.z;
  const int zz = z % 3, mode = z / 3;
  const unsigned short* W = (zz == 0) ? Wq : ((zz == 1) ? Wk : Wv);
  const float* bias = (zz == 0) ? bq : ((zz == 1) ? bk : bv);
  unsigned short* C = mode ? ((zz == 0) ? CqB : ((zz == 1) ? CkB : CvB))
                           : ((zz == 0) ? CqA : ((zz == 1) ? CkA : CvA));
  const int cpart = mt % 3, batch = mt / 3;
  const int widx = mode ? (1 + cpart) : widx_fixed;
  W += (size_t)widx * 512 * 512;
  bias += widx * 512;

  const size_t grow0 = (size_t)batch * 384 + cpart * 128;
  const size_t xrow0 = grow0 * 512;
  const unsigned short* Xbase = X;

  __shared__ __align__(16) unsigned short Xs[1024 * 8];  // 128x64 f16 (16 KB)
  __shared__ __align__(16) unsigned short Wt[1024 * 8];  // 128x64 f16 (16 KB)
  const int tid = threadIdx.x, lane = tid & 63, w = tid >> 6;
  const int col = lane & 15, grp = lane >> 4;
  const int wm = (w >> 1) * 32, wn = (w & 1) * 64;

  const float4v zero4 = {0.f, 0.f, 0.f, 0.f};
  float4v acc[2][4];
#pragma unroll
  for (int i = 0; i < 2; ++i)
#pragma unroll
    for (int j = 0; j < 4; ++j) acc[i][j] = zero4;

  GEMM_CORE(W + (size_t)nt * 128 * 512)

#pragma unroll
  for (int j = 0; j < 4; ++j) {
    const int n = nt * 128 + wn + j * 16 + col;
    const float bj = bias[n];
#pragma unroll
    for (int i = 0; i < 2; ++i)
#pragma unroll
      for (int r = 0; r < 4; ++r) {
        const int m = wm + i * 16 + grp * 4 + r;
        C[(grow0 + m) * 512 + n] = f2h(acc[i][j][r] + bj);
      }
  }
}

// ---------- fusion GEMM: z = diff16 @ W^T ; out = tl2 + diff32*sigmoid(z) ----------
// Same XCD-locality grid: x = mt (96), y = nt (4); id % 8 == mt % 8.
__global__ __launch_bounds__(512) void gemm_fusion(
    const unsigned short* __restrict__ X, const unsigned short* __restrict__ Wf,
    const float* __restrict__ dif, const float* __restrict__ tl2, float* __restrict__ outp) {
  const int mt = blockIdx.x, nt = blockIdx.y;
  const size_t grow0 = (size_t)mt * 128;
  const size_t xrow0 = grow0 * 512;
  const unsigned short* Xbase = X;

  __shared__ __align__(16) unsigned short Xs[1024 * 8];
  __shared__ __align__(16) unsigned short Wt[1024 * 8];
  const int tid = threadIdx.x, lane = tid & 63, w = tid >> 6;
  const int col = lane & 15, grp = lane >> 4;
  const int wm = (w >> 1) * 32, wn = (w & 1) * 64;

  const float4v zero4 = {0.f, 0.f, 0.f, 0.f};
  float4v acc[2][4];
#pragma unroll
  for (int i = 0; i < 2; ++i)
#pragma unroll
    for (int j = 0; j < 4; ++j) acc[i][j] = zero4;

  GEMM_CORE(Wf + (size_t)nt * 128 * 512)

#pragma unroll
  for (int j = 0; j < 4; ++j) {
    const int n = nt * 128 + wn + j * 16 + col;
#pragma unroll
    for (int i = 0; i < 2; ++i)
#pragma unroll
      for (int r = 0; r < 4; ++r) {
        const int m = wm + i * 16 + grp * 4 + r;
        const size_t off = (grow0 + m) * 512 + n;
        const float d = dif[off], t2 = tl2[off];
        const float sg = 1.0f / (1.0f + __expf(-acc[i][j][r]));
        outp[off] = t2 + d * sg;
      }
  }
}

// ---------- attention body, two-pass recompute, 512 threads ----------
// Round-6 champion structure: 2 barriers/block, f32 exp (f16 exp OVERFLOWS:
// |S|~40 -> e~1e15, round-4 failure), LDS-atomic Z, unroll 2.
// PRIO (s_setprio around compute) and VFIRST (V reg-loads before K gather):
// both measured POSITIVE in attn_merged (mixed-phase blocks; r11-r14).
// attn_tail (512 lockstep co-resident blocks) uses the exact round-9 body
// (K-first, no prio) — r13 confirmed V-first/prio regress there.
template <int T, bool PRIO, bool VFIRST>
__device__ __forceinline__ void attn_body(
    const unsigned short* __restrict__ Qb, const unsigned short* __restrict__ Kb,
    const unsigned short* __restrict__ Vb, const float* __restrict__ temp_base,
    const float* add_src,  // may alias diff32
    float* outp, int chunk_elems, int cb, int h, int b,
    const float* tl1_src,  // may alias outp (tail writes tl2 in place)
    unsigned short* diff16, float* diff32,
    unsigned short* KVt, float* Zs) {
  constexpr int NT = T / 16;
  constexpr int NSW = NT / 8;
  constexpr int SLAB = T * 32;
  const int base = b * (384 * 512) + cb * chunk_elems + h * SLAB;
  const float tl2e = temp_base[cb * 16 + h] * 1.4426950408889634f;

  const int tid = threadIdx.x, lane = tid & 63, w = tid >> 6;
  const int col = lane & 15, grp = lane >> 4;

  // zero the Z accumulators (covered by the staging barrier)
  if (tid < NT * 16) Zs[tid] = 0.f;

  half8 vfr[NSW];
  auto load_v = [&]() {
    const unsigned short* Vg = Vb + base;
#pragma unroll
    for (int si = 0; si < NSW; ++si) {
      const int s = (w + si * 8) * 16 + col;
      union { unsigned short u[8]; half8 v; } t8;
#pragma unroll
      for (int i = 0; i < 8; ++i) t8.u[i] = Vg[(size_t)(grp * 8 + i) * T + s];
      vfr[si] = t8.v;
    }
  };
  auto stage_k = [&]() {
    const unsigned short* src = Kb + base;
    constexpr int ITER = (T * 4) / 512;
#pragma unroll
    for (int p = 0; p < ITER; ++p) {
      const int f = p * 512 + tid;
      const int t = f >> 2, blk = (f & 3) * 8;
      unsigned short tmp[8];
#pragma unroll
      for (int i = 0; i < 8; ++i) tmp[i] = src[(size_t)(blk + i) * T + t];
      *(uint4*)&KVt[t * 40 + blk] = *(const uint4*)tmp;
    }
  };
  if constexpr (VFIRST) {
    load_v();
    stage_k();
  } else {
    stage_k();
    load_v();
  }
  __syncthreads();

  const float4v zero4 = {0.f, 0.f, 0.f, 0.f};

  // --- pass 1: full Z via LDS atomics ---
#pragma unroll 2
  for (int tt = 0; tt < NT; ++tt) {
    half8 kf = *(const half8*)&KVt[(tt * 16 + col) * 40 + grp * 8];
    float z0 = 0.f, z1 = 0.f, z2 = 0.f, z3 = 0.f;
    if constexpr (PRIO) setprio<1>();
#pragma unroll
    for (int si = 0; si < NSW; ++si) {
      float4v sv = mfma16x16x32_f16(kf, vfr[si], zero4);
      z0 += fexp2(sv[0] * tl2e);
      z1 += fexp2(sv[1] * tl2e);
      z2 += fexp2(sv[2] * tl2e);
      z3 += fexp2(sv[3] * tl2e);
    }
    if constexpr (PRIO) setprio<0>();
    z0 = row_sum16(z0);
    z1 = row_sum16(z1);
    z2 = row_sum16(z2);
    z3 = row_sum16(z3);
    if (col == 0) {
      float* zp = &Zs[tt * 16 + grp * 4];
      atomicAdd(zp + 0, z0);
      atomicAdd(zp + 1, z1);
      atomicAdd(zp + 2, z2);
      atomicAdd(zp + 3, z3);
    }
  }
  __syncthreads();

  // --- pass 2: recompute S, normalize, PV ---
  const unsigned short* Qsl = Qb + base;
  float4v oacc[NSW][2];
#pragma unroll
  for (int si = 0; si < NSW; ++si) {
    oacc[si][0] = zero4;
    oacc[si][1] = zero4;
  }
#pragma unroll 2
  for (int tt = 0; tt < NT; ++tt) {
    const int toff = tt * 16 + grp * 4;
    half4v qa0 = *(const half4v*)(Qsl + col * T + toff);
    half4v qa1 = *(const half4v*)(Qsl + (16 + col) * T + toff);
    float4v zsv = *(const float4v*)&Zs[tt * 16 + grp * 4];
    const float zi0 = frcp(zsv[0]), zi1 = frcp(zsv[1]), zi2 = frcp(zsv[2]),
                zi3 = frcp(zsv[3]);
    half8 kf = *(const half8*)&KVt[(tt * 16 + col) * 40 + grp * 8];
    if constexpr (PRIO) setprio<1>();
#pragma unroll
    for (int si = 0; si < NSW; ++si) {
      float4v sv = mfma16x16x32_f16(kf, vfr[si], zero4);
      half2v lo = pk_f16(fexp2(sv[0] * tl2e) * zi0, fexp2(sv[1] * tl2e) * zi1);
      half2v hi = pk_f16(fexp2(sv[2] * tl2e) * zi2, fexp2(sv[3] * tl2e) * zi3);
      half4v pb = __builtin_shufflevector(lo, hi, 0, 1, 2, 3);
      oacc[si][0] = mfma16x16x16_f16(qa0, pb, oacc[si][0]);
      oacc[si][1] = mfma16x16x16_f16(qa1, pb, oacc[si][1]);
    }
    if constexpr (PRIO) setprio<0>();
  }

  // --- epilogue ---
#pragma unroll
  for (int si = 0; si < NSW; ++si) {
    const int s = (w + si * 8) * 16 + col;
#pragma unroll
    for (int m0 = 0; m0 < 2; ++m0) {
#pragma unroll
      for (int r = 0; r < 4; ++r) {
        const int dd = m0 * 16 + grp * 4 + r;
        const int off = base + dd * T + s;
        const float o = oacc[si][m0][r];
        float v = o;
        if (add_src) v += add_src[off];
        if (tl1_src) {
          // diff = tl1_final - tl2 = (concat + x_) - (out4 + x_) = concat - out4
          const float d = tl1_src[off] - o;
          diff16[off] = f2h(d);
          diff32[off] = d;  // in-place over add_src[off]: read above precedes
        }
        outp[off] = v;  // in-place over tl1_src[off]: read above precedes
      }
    }
  }
}

// Merged attention: block0 (T=384) + blocks1-3 chunks (T=128) in one dispatch.
// 2048 blocks. HEAVY-FIRST ordering (longest-processing-time scheduling):
// heavy blocks occupy ids 0..511 so they launch first and lights backfill;
// the dispatch tail is a LIGHT block's latency (r14: 131 -> 78.4 us,
// occupancy 27 -> 54%). LDS ~32.3 KB; PRIO=true + VFIRST=true.
__global__ __launch_bounds__(512) void attn_merged(
    const unsigned short* __restrict__ Q0, const unsigned short* __restrict__ K0,
    const unsigned short* __restrict__ V0, const unsigned short* __restrict__ Qc,
    const unsigned short* __restrict__ Kc, const unsigned short* __restrict__ Vc,
    const float* __restrict__ temp, float* xres, float* tl1) {
  __shared__ __align__(16) unsigned short Ks[384 * 40];
  __shared__ __align__(16) float Zs[24 * 16];
  const int id = blockIdx.x + 16 * (blockIdx.y + 32 * blockIdx.z);
  if (id < 512) {
    const int h = id & 15, b = id >> 4;
    attn_body<384, true, true>(Q0, K0, V0, temp, nullptr, xres, 0, 0, h, b,
                               nullptr, nullptr, nullptr, Ks, Zs);
  } else {
    const int idl = id - 512;
    const int cb = idl >> 9;       // 0..2 (512 blocks per chunk part)
    const int rest = idl & 511;
    const int h = rest & 15, b = rest >> 4;
    attn_body<128, true, true>(Qc, Kc, Vc, temp + 16, nullptr, tl1, 128 * 512,
                               cb, h, b, nullptr, nullptr, nullptr, Ks, Zs);
  }
}

// Tail attention (block 4): tl2 = out4 + x_ written in place into tl1 buffer,
// diff (f32 and f16) written; diff32 lands in place over x_ (add_src).
// PRIO=false + VFIRST=false: bit-exact round-9 body — 512 lockstep co-resident
// blocks are the regime where both micro-levers measured negative (r11-r13).
__global__ __launch_bounds__(512) void attn_tail(
    const unsigned short* __restrict__ Q, const unsigned short* __restrict__ K,
    const unsigned short* __restrict__ V, const float* __restrict__ temp4,
    const float* add_src, float* tl12, unsigned short* __restrict__ diff16,
    float* diff32) {
  __shared__ __align__(16) unsigned short Ks[384 * 40];
  __shared__ __align__(16) float Zs[24 * 16];
  attn_body<384, false, false>(Q, K, V, temp4, add_src, tl12, 0, 0, blockIdx.x,
                               blockIdx.y, tl12, diff16, diff32, Ks, Zs);
}

// ---------- layernorm over rows of 512 of (a + c) -> fp16 ----------
__global__ __launch_bounds__(256) void ln_kernel(const float* __restrict__ a,
                                                 const float* __restrict__ c,
                                                 const float* __restrict__ g,
                                                 const float* __restrict__ bb,
                                                 unsigned short* __restrict__ y) {
  const int row = blockIdx.x * 4 + (threadIdx.x >> 6);
  const int lane = threadIdx.x & 63;
  const float* ar = a + (size_t)row * 512;
  const float* cr = c + (size_t)row * 512;
  float4 a0 = *(const float4*)&ar[lane * 8];
  float4 a1 = *(const float4*)&ar[lane * 8 + 4];
  float4 c0 = *(const float4*)&cr[lane * 8];
  float4 c1 = *(const float4*)&cr[lane * 8 + 4];
  float4 v0, v1;
  v0.x = a0.x + c0.x; v0.y = a0.y + c0.y; v0.z = a0.z + c0.z; v0.w = a0.w + c0.w;
  v1.x = a1.x + c1.x; v1.y = a1.y + c1.y; v1.z = a1.z + c1.z; v1.w = a1.w + c1.w;
  float s = v0.x + v0.y + v0.z + v0.w + v1.x + v1.y + v1.z + v1.w;
  float q = v0.x * v0.x + v0.y * v0.y + v0.z * v0.z + v0.w * v0.w +
            v1.x * v1.x + v1.y * v1.y + v1.z * v1.z + v1.w * v1.w;
#pragma unroll
  for (int m = 1; m < 64; m <<= 1) {
    s += __shfl_xor(s, m);
    q += __shfl_xor(q, m);
  }
  const float mean = s * (1.0f / 512.0f);
  const float var = q * (1.0f / 512.0f) - mean * mean;
  const float rs = rsqrtf(var + 1e-5f);
  float4 g0 = *(const float4*)&g[lane * 8];
  float4 g1 = *(const float4*)&g[lane * 8 + 4];
  float4 b0 = *(const float4*)&bb[lane * 8];
  float4 b1 = *(const float4*)&bb[lane * 8 + 4];
  uint4 o;
  o.x = (unsigned)f2h((v0.x - mean) * rs * g0.x + b0.x) |
        ((unsigned)f2h((v0.y - mean) * rs * g0.y + b0.y) << 16);
  o.y = (unsigned)f2h((v0.z - mean) * rs * g0.z + b0.z) |
        ((unsigned)f2h((v0.w - mean) * rs * g0.w + b0.w) << 16);
  o.z = (unsigned)f2h((v1.x - mean) * rs * g1.x + b1.x) |
        ((unsigned)f2h((v1.y - mean) * rs * g1.y + b1.y) << 16);
  o.w = (unsigned)f2h((v1.z - mean) * rs * g1.z + b1.z) |
        ((unsigned)f2h((v1.w - mean) * rs * g1.w + b1.w) << 16);
  *(uint4*)&y[(size_t)row * 512 + lane * 8] = o;
}

// ---------- launch ----------
extern "C" void kernel_launch(void* const* d_in, const int* in_sizes, int n_in,
                              void* d_out, int out_size, void* d_ws, size_t ws_size,
                              hipStream_t stream) {
  const float* x = (const float*)d_in[0];
  const float* qw = (const float*)d_in[1];
  const float* qb = (const float*)d_in[2];
  const float* kw = (const float*)d_in[3];
  const float* kb = (const float*)d_in[4];
  const float* vw = (const float*)d_in[5];
  const float* vb = (const float*)d_in[6];
  const float* temp = (const float*)d_in[7];
  const float* ln_g = (const float*)d_in[8];
  const float* ln_b = (const float*)d_in[9];
  const float* fus_w = (const float*)d_in[10];
  // fus_b (d_in[11]) cancels in the 2-way softmax; num_heads (d_in[12]) fixed at 16
  float* out = (float*)d_out;

  const size_t NE = (size_t)32 * 384 * 512;  // 6291456
  const size_t WE = (size_t)5 * 512 * 512;   // 1310720

  char* p = (char*)d_ws;
  auto alloc = [&](size_t bytes) {
    char* r = p;
    p += (bytes + 255) & ~(size_t)255;
    return r;
  };
  unsigned short* xb = (unsigned short*)alloc(NE * 2);
  unsigned short* wqb = (unsigned short*)alloc(WE * 2);
  unsigned short* wkb = (unsigned short*)alloc(WE * 2);
  unsigned short* wvb = (unsigned short*)alloc(WE * 2);
  unsigned short* fwb = (unsigned short*)alloc((size_t)512 * 512 * 2);
  unsigned short* Qb = (unsigned short*)alloc(NE * 2);
  unsigned short* Kb = (unsigned short*)alloc(NE * 2);
  unsigned short* Vb = (unsigned short*)alloc(NE * 2);
  float* xres = (float*)alloc(NE * 4);  // x_ , later diff32 (in place)
  float* tl1 = (float*)alloc(NE * 4);   // raw concat, later tl2 (in place)
  unsigned short* yb = (unsigned short*)alloc(NE * 2);  // Qc, LN out, later diff16

  // chunk QKV scratch: Qc shares yb; Kc/Vc live in d_out (exactly 2*NE*2 B),
  // overwritten by the final fusion GEMM.
  unsigned short* Qc = yb;
  unsigned short* Kc = (unsigned short*)out;
  unsigned short* Vc = Kc + NE;

  // all converts in one dispatch
  cvt_multi<<<dim3((int)(NE / 4 / 256), 5), 256, 0, stream>>>(
      x, xb, (int)(NE / 4), qw, wqb, kw, wkb, vw, wvb, (int)(WE / 4), fus_w, fwb,
      512 * 512 / 4);

  // projections for block 0 (-> set A) and blocks 1-3 (-> set B), one dispatch
  // grid (mt=96, nt=4, z=6): id%8 == mt%8 -> X-tile sharers pinned per-XCD
  gemm_qkv6<<<dim3(96, 4, 6), 512, 0, stream>>>(xb, wqb, wkb, wvb, qb, kb, vb,
                                                Qb, Kb, Vb, Qc, Kc, Vc, 0);
  // attention block0 -> x_ (xres) and blocks1-3 -> raw concat (tl1), merged
  attn_merged<<<dim3(16, 32, 4), 512, 0, stream>>>(Qb, Kb, Vb, Qc, Kc, Vc, temp,
                                                   xres, tl1);
  // layernorm(tl1raw + x_) -> yb (fp16)
  ln_kernel<<<12288 / 4, 256, 0, stream>>>(tl1, xres, ln_g, ln_b, yb);
  // block 4 projections (set A reused)
  gemm_qkv6<<<dim3(96, 4, 3), 512, 0, stream>>>(yb, wqb, wkb, wvb, qb, kb, vb,
                                                Qb, Kb, Vb, Qb, Kb, Vb, 4);
  // block 4 attention: tl2 -> tl1 (in place), diff16 -> yb, diff32 -> xres
  attn_tail<<<dim3(16, 32, 1), 512, 0, stream>>>(Qb, Kb, Vb, temp + 64, xres, tl1,
                                                 yb, xres);
  // fusion: out = tl2 + diff32 * sigmoid(diff16 @ fus_w^T)
  gemm_fusion<<<dim3(96, 4), 512, 0, stream>>>(yb, fwb, xres, tl1, out);

  (void)in_sizes; (void)n_in; (void)out_size; (void)ws_size;
}